// Round 1
// baseline (874.349 us; speedup 1.0000x reference)
//
#include <hip/hip_runtime.h>
#include <cstddef>
#include <cstdint>

// ---------------------------------------------------------------------------
// GraphConv x3  (DGL norm='both', per-edge weight)
//   coef[e] = ew[e] * out_norm[src[e]]          (layer-independent)
//   layer fin<=fout:  Y = inorm .* CSR-agg(coef, h);  h' = relu(Y@W + b)
//   layer fin>fout :  G = h@W;  out = inorm .* CSR-agg(coef, G) + b
// ---------------------------------------------------------------------------

__global__ void k_degrees(const int* __restrict__ src, const int* __restrict__ dst,
                          int* __restrict__ outdeg, int* __restrict__ indeg, int E) {
    int i = blockIdx.x * blockDim.x + threadIdx.x;
    if (i < E) {
        atomicAdd(&outdeg[src[i]], 1);
        atomicAdd(&indeg[dst[i]], 1);
    }
}

__global__ void k_norms(const int* __restrict__ outdeg, const int* __restrict__ indeg,
                        float* __restrict__ onorm, float* __restrict__ inorm, int N) {
    int i = blockIdx.x * blockDim.x + threadIdx.x;
    if (i < N) {
        int od = outdeg[i]; if (od < 1) od = 1;
        int id = indeg[i];  if (id < 1) id = 1;
        onorm[i] = 1.0f / sqrtf((float)od);
        inorm[i] = 1.0f / sqrtf((float)id);
    }
}

// exclusive scan, 256/block, emit block sums
__global__ void k_scan_block(const int* __restrict__ in, int* __restrict__ out,
                             int* __restrict__ bsum, int N) {
    __shared__ int s[256];
    const int t = threadIdx.x;
    const int i = blockIdx.x * 256 + t;
    const int v = (i < N) ? in[i] : 0;
    s[t] = v;
    __syncthreads();
    for (int off = 1; off < 256; off <<= 1) {
        int x = (t >= off) ? s[t - off] : 0;
        __syncthreads();
        s[t] += x;
        __syncthreads();
    }
    if (i < N) out[i] = s[t] - v;       // exclusive
    if (t == 255) bsum[blockIdx.x] = s[255];
}

// single-block exclusive scan over block sums (nb <= 512)
__global__ void k_scan_bsum(const int* __restrict__ bsum, int* __restrict__ boff, int nb) {
    __shared__ int s[512];
    const int t = threadIdx.x;
    const int v = (t < nb) ? bsum[t] : 0;
    s[t] = v;
    __syncthreads();
    for (int off = 1; off < 512; off <<= 1) {
        int x = (t >= off) ? s[t - off] : 0;
        __syncthreads();
        s[t] += x;
        __syncthreads();
    }
    if (t < nb) boff[t] = s[t] - v;     // exclusive
}

__global__ void k_finalize_rows(int* __restrict__ row, const int* __restrict__ boff,
                                int N, int E) {
    int i = blockIdx.x * blockDim.x + threadIdx.x;
    if (i < N) row[i] += boff[i >> 8];
    if (i == 0) row[N] = E;
}

__global__ void k_fill(const int* __restrict__ src, const int* __restrict__ dst,
                       const float* __restrict__ ew, const float* __restrict__ onorm,
                       const int* __restrict__ row, int* __restrict__ cursor,
                       int* __restrict__ csr_src, float* __restrict__ csr_coef, int E) {
    int i = blockIdx.x * blockDim.x + threadIdx.x;
    if (i < E) {
        int d = dst[i];
        int s = src[i];
        int pos = row[d] + atomicAdd(&cursor[d], 1);
        csr_src[pos]  = s;
        csr_coef[pos] = ew[i] * onorm[s];
    }
}

// one wave per node, width 128 (float2 per lane)
__global__ void __launch_bounds__(256)
k_agg128(const float* __restrict__ h, const int* __restrict__ row,
         const int* __restrict__ csr_src, const float* __restrict__ csr_coef,
         const float* __restrict__ inorm, float* __restrict__ out, int N) {
    const int node = (int)((blockIdx.x * blockDim.x + threadIdx.x) >> 6);
    const int lane = threadIdx.x & 63;
    if (node >= N) return;
    int p = row[node];
    const int e = row[node + 1];
    const int col = lane * 2;
    float ax = 0.f, ay = 0.f;
    for (; p + 2 <= e; p += 2) {
        const int   s0 = csr_src[p],     s1 = csr_src[p + 1];
        const float c0 = csr_coef[p],    c1 = csr_coef[p + 1];
        const float2 v0 = *(const float2*)(h + (size_t)s0 * 128 + col);
        const float2 v1 = *(const float2*)(h + (size_t)s1 * 128 + col);
        ax = fmaf(c0, v0.x, ax); ay = fmaf(c0, v0.y, ay);
        ax = fmaf(c1, v1.x, ax); ay = fmaf(c1, v1.y, ay);
    }
    if (p < e) {
        const float c = csr_coef[p];
        const float2 v = *(const float2*)(h + (size_t)csr_src[p] * 128 + col);
        ax = fmaf(c, v.x, ax); ay = fmaf(c, v.y, ay);
    }
    const float nn = inorm[node];
    float2 r; r.x = ax * nn; r.y = ay * nn;
    *(float2*)(out + (size_t)node * 128 + col) = r;
}

// one wave per node, width 64, fused bias, writes final output
__global__ void __launch_bounds__(256)
k_agg64(const float* __restrict__ h, const int* __restrict__ row,
        const int* __restrict__ csr_src, const float* __restrict__ csr_coef,
        const float* __restrict__ inorm, const float* __restrict__ bias,
        float* __restrict__ out, int N) {
    const int node = (int)((blockIdx.x * blockDim.x + threadIdx.x) >> 6);
    const int lane = threadIdx.x & 63;
    if (node >= N) return;
    int p = row[node];
    const int e = row[node + 1];
    float acc = 0.f;
    for (; p + 2 <= e; p += 2) {
        const int   s0 = csr_src[p],  s1 = csr_src[p + 1];
        const float c0 = csr_coef[p], c1 = csr_coef[p + 1];
        acc = fmaf(c0, h[(size_t)s0 * 64 + lane], acc);
        acc = fmaf(c1, h[(size_t)s1 * 64 + lane], acc);
    }
    if (p < e) acc = fmaf(csr_coef[p], h[(size_t)csr_src[p] * 64 + lane], acc);
    out[(size_t)node * 64 + lane] = acc * inorm[node] + bias[lane];
}

// C[N x FOUT] = A[N x 128] @ W[128 x FOUT]  (+bias, +relu)
// 64-node x 64-out tile per block; As staged transposed [k][n] (broadcast float4
// reads), Ws [k][o] (stride-1 scalar reads). 16 nodes x 1 out per thread.
template <int FOUT, bool RELU, bool BIAS>
__global__ void __launch_bounds__(256)
k_gemm(const float* __restrict__ A, const float* __restrict__ W,
       const float* __restrict__ bias, float* __restrict__ C, int N) {
    __shared__ float As[128][64];   // [k][n]
    __shared__ float Ws[128][64];   // [k][o]
    const int t  = threadIdx.x;
    const int n0 = blockIdx.x * 64;
    const int o0 = blockIdx.y * 64;

    {   // A tile: 64 rows x 128 cols, transpose into As[k][n]
        const int c4 = t & 31;      // k-chunk
        const int rb = t >> 5;      // 0..7
        #pragma unroll
        for (int r = 0; r < 8; ++r) {
            const int n  = r * 8 + rb;
            const int gn = n0 + n;
            float4 v = make_float4(0.f, 0.f, 0.f, 0.f);
            if (gn < N) v = *(const float4*)(A + (size_t)gn * 128 + c4 * 4);
            As[c4 * 4 + 0][n] = v.x;
            As[c4 * 4 + 1][n] = v.y;
            As[c4 * 4 + 2][n] = v.z;
            As[c4 * 4 + 3][n] = v.w;
        }
    }
    {   // W tile: 128 rows x 64 cols
        const int c4 = t & 15;
        const int kb = t >> 4;      // 0..15
        #pragma unroll
        for (int r = 0; r < 8; ++r) {
            const int k = r * 16 + kb;
            *(float4*)&Ws[k][c4 * 4] = *(const float4*)(W + (size_t)k * FOUT + o0 + c4 * 4);
        }
    }
    __syncthreads();

    const int o  = t & 63;          // out col within tile (per lane)
    const int ng = t >> 6;          // node group (wave-uniform)
    float acc[16];
    #pragma unroll
    for (int i = 0; i < 16; ++i) acc[i] = 0.f;

    #pragma unroll 4
    for (int k = 0; k < 128; ++k) {
        const float  b  = Ws[k][o];
        const float4 a0 = *(const float4*)&As[k][ng * 16 + 0];
        const float4 a1 = *(const float4*)&As[k][ng * 16 + 4];
        const float4 a2 = *(const float4*)&As[k][ng * 16 + 8];
        const float4 a3 = *(const float4*)&As[k][ng * 16 + 12];
        acc[0]  = fmaf(a0.x, b, acc[0]);
        acc[1]  = fmaf(a0.y, b, acc[1]);
        acc[2]  = fmaf(a0.z, b, acc[2]);
        acc[3]  = fmaf(a0.w, b, acc[3]);
        acc[4]  = fmaf(a1.x, b, acc[4]);
        acc[5]  = fmaf(a1.y, b, acc[5]);
        acc[6]  = fmaf(a1.z, b, acc[6]);
        acc[7]  = fmaf(a1.w, b, acc[7]);
        acc[8]  = fmaf(a2.x, b, acc[8]);
        acc[9]  = fmaf(a2.y, b, acc[9]);
        acc[10] = fmaf(a2.z, b, acc[10]);
        acc[11] = fmaf(a2.w, b, acc[11]);
        acc[12] = fmaf(a3.x, b, acc[12]);
        acc[13] = fmaf(a3.y, b, acc[13]);
        acc[14] = fmaf(a3.z, b, acc[14]);
        acc[15] = fmaf(a3.w, b, acc[15]);
    }

    float bb = 0.f;
    if (BIAS) bb = bias[o0 + o];
    #pragma unroll
    for (int i = 0; i < 16; ++i) {
        const int gn = n0 + ng * 16 + i;
        if (gn < N) {
            float v = acc[i] + bb;
            if (RELU) v = v > 0.f ? v : 0.f;
            C[(size_t)gn * FOUT + o0 + o] = v;
        }
    }
}

extern "C" void kernel_launch(void* const* d_in, const int* in_sizes, int n_in,
                              void* d_out, int out_size, void* d_ws, size_t ws_size,
                              hipStream_t stream) {
    const float* feat = (const float*)d_in[0];
    const int*   src  = (const int*)d_in[1];
    const int*   dst  = (const int*)d_in[2];
    const float* ew   = (const float*)d_in[3];
    const float* W0   = (const float*)d_in[4];
    const float* b0   = (const float*)d_in[5];
    const float* W1   = (const float*)d_in[6];
    const float* b1   = (const float*)d_in[7];
    const float* W2   = (const float*)d_in[8];
    const float* b2   = (const float*)d_in[9];
    float* out = (float*)d_out;

    const int N = in_sizes[0] / 128;
    const int E = in_sizes[1];

    uint8_t* wp = (uint8_t*)d_ws;
    auto alloc = [&](size_t bytes) {
        uint8_t* r = wp;
        wp += (bytes + 511) & ~(size_t)511;
        return r;
    };
    float* X        = (float*)alloc((size_t)N * 128 * 4);
    float* Y        = (float*)alloc((size_t)N * 128 * 4);
    int*   csr_src  = (int*)alloc((size_t)E * 4);
    float* csr_coef = (float*)alloc((size_t)E * 4);
    int*   row      = (int*)alloc((size_t)(N + 1) * 4);
    int*   cursor   = (int*)alloc((size_t)N * 4);
    int*   indeg    = (int*)alloc((size_t)N * 4);
    int*   outdeg   = (int*)alloc((size_t)N * 4);
    float* onorm    = (float*)alloc((size_t)N * 4);
    float* inorm    = (float*)alloc((size_t)N * 4);
    int*   bsum     = (int*)alloc(4096);
    int*   boff     = (int*)alloc(4096);

    hipMemsetAsync(indeg,  0, (size_t)N * 4, stream);
    hipMemsetAsync(outdeg, 0, (size_t)N * 4, stream);
    hipMemsetAsync(cursor, 0, (size_t)N * 4, stream);

    const int eb = (E + 255) / 256;
    const int nb = (N + 255) / 256;

    k_degrees<<<eb, 256, 0, stream>>>(src, dst, outdeg, indeg, E);
    k_norms<<<nb, 256, 0, stream>>>(outdeg, indeg, onorm, inorm, N);
    k_scan_block<<<nb, 256, 0, stream>>>(indeg, row, bsum, N);
    k_scan_bsum<<<1, 512, 0, stream>>>(bsum, boff, nb);
    k_finalize_rows<<<nb, 256, 0, stream>>>(row, boff, N, E);
    k_fill<<<eb, 256, 0, stream>>>(src, dst, ew, onorm, row, cursor, csr_src, csr_coef, E);

    const int ab = (N + 3) / 4;          // 4 waves (nodes) per block
    dim3 g128((N + 63) / 64, 2);
    dim3 g64((N + 63) / 64, 1);

    // layer 0: agg(features) -> Y ; X = relu(Y@W0 + b0)
    k_agg128<<<ab, 256, 0, stream>>>(feat, row, csr_src, csr_coef, inorm, Y, N);
    k_gemm<128, true, true><<<g128, 256, 0, stream>>>(Y, W0, b0, X, N);
    // layer 1
    k_agg128<<<ab, 256, 0, stream>>>(X, row, csr_src, csr_coef, inorm, Y, N);
    k_gemm<128, true, true><<<g128, 256, 0, stream>>>(Y, W1, b1, X, N);
    // layer 2: GEMM first (128 > 64), then aggregate + bias into d_out
    k_gemm<64, false, false><<<g64, 256, 0, stream>>>(X, W2, nullptr, Y, N);
    k_agg64<<<ab, 256, 0, stream>>>(Y, row, csr_src, csr_coef, inorm, b2, out, N);
}

// Round 2
// 684.961 us; speedup vs baseline: 1.2765x; 1.2765x over previous
//
#include <hip/hip_runtime.h>
#include <cstddef>
#include <cstdint>

typedef float f4 __attribute__((ext_vector_type(4)));
typedef unsigned long long u64;

__device__ __forceinline__ f4 ldnt4(const float* p) {
    return __builtin_nontemporal_load((const f4*)p);
}
__device__ __forceinline__ u64 ldnt8(const void* p) {
    return __builtin_nontemporal_load((const u64*)p);
}

// ---------------------------------------------------------------------------
// GraphConv x3 (DGL norm='both', per-edge weight)
//   coef[e] = ew[e] * out_norm[src[e]]   (layer-independent, fused into CSR)
// ---------------------------------------------------------------------------

__global__ void k_degrees(const int* __restrict__ src, const int* __restrict__ dst,
                          int* __restrict__ outdeg, int* __restrict__ indeg, int E) {
    int i = blockIdx.x * blockDim.x + threadIdx.x;
    if (i < E) {
        atomicAdd(&outdeg[src[i]], 1);
        atomicAdd(&indeg[dst[i]], 1);
    }
}

__global__ void k_norms(const int* __restrict__ outdeg, const int* __restrict__ indeg,
                        float* __restrict__ onorm, float* __restrict__ inorm, int N) {
    int i = blockIdx.x * blockDim.x + threadIdx.x;
    if (i < N) {
        int od = outdeg[i]; if (od < 1) od = 1;
        int id = indeg[i];  if (id < 1) id = 1;
        onorm[i] = 1.0f / sqrtf((float)od);
        inorm[i] = 1.0f / sqrtf((float)id);
    }
}

__global__ void k_scan_block(const int* __restrict__ in, int* __restrict__ out,
                             int* __restrict__ bsum, int N) {
    __shared__ int s[256];
    const int t = threadIdx.x;
    const int i = blockIdx.x * 256 + t;
    const int v = (i < N) ? in[i] : 0;
    s[t] = v;
    __syncthreads();
    for (int off = 1; off < 256; off <<= 1) {
        int x = (t >= off) ? s[t - off] : 0;
        __syncthreads();
        s[t] += x;
        __syncthreads();
    }
    if (i < N) out[i] = s[t] - v;
    if (t == 255) bsum[blockIdx.x] = s[255];
}

__global__ void k_scan_bsum(const int* __restrict__ bsum, int* __restrict__ boff, int nb) {
    __shared__ int s[512];
    const int t = threadIdx.x;
    const int v = (t < nb) ? bsum[t] : 0;
    s[t] = v;
    __syncthreads();
    for (int off = 1; off < 512; off <<= 1) {
        int x = (t >= off) ? s[t - off] : 0;
        __syncthreads();
        s[t] += x;
        __syncthreads();
    }
    if (t < nb) boff[t] = s[t] - v;
}

__global__ void k_finalize_rows(int* __restrict__ row, const int* __restrict__ boff,
                                int N, int E) {
    int i = blockIdx.x * blockDim.x + threadIdx.x;
    if (i < N) row[i] += boff[i >> 8];
    if (i == 0) row[N] = E;
}

// csr entry = int2{src, bits(ew*onorm[src])}, one 8B store per edge
__global__ void k_fill(const int* __restrict__ src, const int* __restrict__ dst,
                       const float* __restrict__ ew, const float* __restrict__ onorm,
                       const int* __restrict__ row, int* __restrict__ cursor,
                       int2* __restrict__ csr, int E) {
    int i = blockIdx.x * blockDim.x + threadIdx.x;
    if (i < E) {
        int d = dst[i];
        int s = src[i];
        int pos = row[d] + atomicAdd(&cursor[d], 1);
        float c = ew[i] * onorm[s];
        u64 v = ((u64)(unsigned)__float_as_int(c) << 32) | (unsigned)s;
        __builtin_nontemporal_store(v, (u64*)&csr[pos]);
    }
}

// one wave per node, width 128: 2 half-waves own alternating edges,
// each half-wave reads a full 512B row as 32 x float4
__global__ void __launch_bounds__(256)
k_agg128(const float* __restrict__ h, const int* __restrict__ row,
         const int2* __restrict__ csr, const float* __restrict__ inorm,
         float* __restrict__ out, int N) {
    const int node = (int)((blockIdx.x * blockDim.x + threadIdx.x) >> 6);
    if (node >= N) return;
    const int lane = threadIdx.x & 63;
    const int half = lane >> 5;
    const int col = (lane & 31) * 4;
    int p = row[node];
    const int e = row[node + 1];
    f4 acc = {0.f, 0.f, 0.f, 0.f};
    for (; p + 4 <= e; p += 4) {
        const u64 u0 = ldnt8(&csr[p + half]);
        const u64 u1 = ldnt8(&csr[p + 2 + half]);
        const f4 v0 = *(const f4*)(h + (size_t)(int)u0 * 128 + col);
        const f4 v1 = *(const f4*)(h + (size_t)(int)u1 * 128 + col);
        const float c0 = __int_as_float((int)(u0 >> 32));
        const float c1 = __int_as_float((int)(u1 >> 32));
        acc.x = fmaf(c0, v0.x, acc.x); acc.y = fmaf(c0, v0.y, acc.y);
        acc.z = fmaf(c0, v0.z, acc.z); acc.w = fmaf(c0, v0.w, acc.w);
        acc.x = fmaf(c1, v1.x, acc.x); acc.y = fmaf(c1, v1.y, acc.y);
        acc.z = fmaf(c1, v1.z, acc.z); acc.w = fmaf(c1, v1.w, acc.w);
    }
    for (; p < e; p += 2) {
        const int q = p + half;
        if (q < e) {
            const u64 u0 = *(const u64*)&csr[q];
            const f4 v = *(const f4*)(h + (size_t)(int)u0 * 128 + col);
            const float c = __int_as_float((int)(u0 >> 32));
            acc.x = fmaf(c, v.x, acc.x); acc.y = fmaf(c, v.y, acc.y);
            acc.z = fmaf(c, v.z, acc.z); acc.w = fmaf(c, v.w, acc.w);
        }
    }
    acc.x += __shfl_xor(acc.x, 32);
    acc.y += __shfl_xor(acc.y, 32);
    acc.z += __shfl_xor(acc.z, 32);
    acc.w += __shfl_xor(acc.w, 32);
    if (half == 0) {
        const float nn = inorm[node];
        f4 r = {acc.x * nn, acc.y * nn, acc.z * nn, acc.w * nn};
        __builtin_nontemporal_store(r, (f4*)(out + (size_t)node * 128 + col));
    }
}

// one wave per node, width 64: 4 quarter-waves own alternating edges,
// each quarter reads a full 256B row as 16 x float4; fused bias, final output
__global__ void __launch_bounds__(256)
k_agg64(const float* __restrict__ h, const int* __restrict__ row,
        const int2* __restrict__ csr, const float* __restrict__ inorm,
        const float* __restrict__ bias, float* __restrict__ out, int N) {
    const int node = (int)((blockIdx.x * blockDim.x + threadIdx.x) >> 6);
    if (node >= N) return;
    const int lane = threadIdx.x & 63;
    const int q = lane >> 4;
    const int col = (lane & 15) * 4;
    int p = row[node];
    const int e = row[node + 1];
    f4 acc = {0.f, 0.f, 0.f, 0.f};
    for (; p + 8 <= e; p += 8) {
        const u64 u0 = ldnt8(&csr[p + q]);
        const u64 u1 = ldnt8(&csr[p + 4 + q]);
        const f4 v0 = *(const f4*)(h + (size_t)(int)u0 * 64 + col);
        const f4 v1 = *(const f4*)(h + (size_t)(int)u1 * 64 + col);
        const float c0 = __int_as_float((int)(u0 >> 32));
        const float c1 = __int_as_float((int)(u1 >> 32));
        acc.x = fmaf(c0, v0.x, acc.x); acc.y = fmaf(c0, v0.y, acc.y);
        acc.z = fmaf(c0, v0.z, acc.z); acc.w = fmaf(c0, v0.w, acc.w);
        acc.x = fmaf(c1, v1.x, acc.x); acc.y = fmaf(c1, v1.y, acc.y);
        acc.z = fmaf(c1, v1.z, acc.z); acc.w = fmaf(c1, v1.w, acc.w);
    }
    for (; p < e; p += 4) {
        const int idx = p + q;
        if (idx < e) {
            const u64 u0 = *(const u64*)&csr[idx];
            const f4 v = *(const f4*)(h + (size_t)(int)u0 * 64 + col);
            const float c = __int_as_float((int)(u0 >> 32));
            acc.x = fmaf(c, v.x, acc.x); acc.y = fmaf(c, v.y, acc.y);
            acc.z = fmaf(c, v.z, acc.z); acc.w = fmaf(c, v.w, acc.w);
        }
    }
    acc.x += __shfl_xor(acc.x, 16); acc.y += __shfl_xor(acc.y, 16);
    acc.z += __shfl_xor(acc.z, 16); acc.w += __shfl_xor(acc.w, 16);
    acc.x += __shfl_xor(acc.x, 32); acc.y += __shfl_xor(acc.y, 32);
    acc.z += __shfl_xor(acc.z, 32); acc.w += __shfl_xor(acc.w, 32);
    if (lane < 16) {
        const float nn = inorm[node];
        const f4 bv = *(const f4*)(bias + col);
        f4 r = {acc.x * nn + bv.x, acc.y * nn + bv.y,
                acc.z * nn + bv.z, acc.w * nn + bv.w};
        __builtin_nontemporal_store(r, (f4*)(out + (size_t)node * 64 + col));
    }
}

// C[N x BN] = A[N x 128] @ W[128 x BN] (+bias, +relu)
// BM=128 tile, BK=32, 256 threads, each computes 8 x TN outputs.
template <int BN, int TN, bool RELU, bool BIAS>
__global__ void __launch_bounds__(256)
k_gemm(const float* __restrict__ A, const float* __restrict__ W,
       const float* __restrict__ bias, float* __restrict__ C, int N) {
    __shared__ float As[32][132];   // [k][m], padded to keep 16B alignment
    __shared__ float Ws[32][BN];    // [k][o]
    const int t   = threadIdx.x;
    const int bm0 = blockIdx.x * 128;
    const int tx  = t & 15;         // out-col group
    const int ty  = t >> 4;         // row group

    float acc[8][TN];
    #pragma unroll
    for (int i = 0; i < 8; ++i)
        #pragma unroll
        for (int j = 0; j < TN; ++j) acc[i][j] = 0.f;

    for (int kt = 0; kt < 4; ++kt) {
        __syncthreads();
        #pragma unroll
        for (int r = 0; r < 4; ++r) {       // A tile: 128 rows x 32 k, transposed
            const int idx = r * 256 + t;
            const int m = idx >> 3, f = idx & 7;
            const int gm = bm0 + m;
            f4 v = {0.f, 0.f, 0.f, 0.f};
            if (gm < N) v = ldnt4(A + (size_t)gm * 128 + kt * 32 + f * 4);
            As[f * 4 + 0][m] = v.x;
            As[f * 4 + 1][m] = v.y;
            As[f * 4 + 2][m] = v.z;
            As[f * 4 + 3][m] = v.w;
        }
        #pragma unroll
        for (int r = 0; r < (BN == 128 ? 4 : 2); ++r) {   // W tile: 32 k x BN
            const int idx = r * 256 + t;
            const int kk = idx / (BN / 4), f = idx % (BN / 4);
            *(f4*)&Ws[kk][f * 4] = *(const f4*)(W + (size_t)(kt * 32 + kk) * BN + f * 4);
        }
        __syncthreads();
        #pragma unroll
        for (int k = 0; k < 32; ++k) {
            const f4 a0 = *(const f4*)&As[k][ty * 8];
            const f4 a1 = *(const f4*)&As[k][ty * 8 + 4];
            const float a[8] = {a0.x, a0.y, a0.z, a0.w, a1.x, a1.y, a1.z, a1.w};
            float b[TN];
            *(f4*)&b[0] = *(const f4*)&Ws[k][tx * TN];
            if (TN == 8) *(f4*)&b[4] = *(const f4*)&Ws[k][tx * TN + 4];
            #pragma unroll
            for (int i = 0; i < 8; ++i)
                #pragma unroll
                for (int j = 0; j < TN; ++j)
                    acc[i][j] = fmaf(a[i], b[j], acc[i][j]);
        }
    }

    float bb[TN];
    #pragma unroll
    for (int j = 0; j < TN; ++j) bb[j] = BIAS ? bias[tx * TN + j] : 0.f;

    #pragma unroll
    for (int i = 0; i < 8; ++i) {
        const int gm = bm0 + ty * 8 + i;
        if (gm < N) {
            #pragma unroll
            for (int j0 = 0; j0 < TN; j0 += 4) {
                f4 v = {acc[i][j0 + 0] + bb[j0 + 0], acc[i][j0 + 1] + bb[j0 + 1],
                        acc[i][j0 + 2] + bb[j0 + 2], acc[i][j0 + 3] + bb[j0 + 3]};
                if (RELU) {
                    v.x = v.x > 0.f ? v.x : 0.f;
                    v.y = v.y > 0.f ? v.y : 0.f;
                    v.z = v.z > 0.f ? v.z : 0.f;
                    v.w = v.w > 0.f ? v.w : 0.f;
                }
                __builtin_nontemporal_store(v, (f4*)(C + (size_t)gm * BN + tx * TN + j0));
            }
        }
    }
}

extern "C" void kernel_launch(void* const* d_in, const int* in_sizes, int n_in,
                              void* d_out, int out_size, void* d_ws, size_t ws_size,
                              hipStream_t stream) {
    const float* feat = (const float*)d_in[0];
    const int*   src  = (const int*)d_in[1];
    const int*   dst  = (const int*)d_in[2];
    const float* ew   = (const float*)d_in[3];
    const float* W0   = (const float*)d_in[4];
    const float* b0   = (const float*)d_in[5];
    const float* W1   = (const float*)d_in[6];
    const float* b1   = (const float*)d_in[7];
    const float* W2   = (const float*)d_in[8];
    const float* b2   = (const float*)d_in[9];
    float* out = (float*)d_out;

    const int N = in_sizes[0] / 128;
    const int E = in_sizes[1];

    uint8_t* wp = (uint8_t*)d_ws;
    auto alloc = [&](size_t bytes) {
        uint8_t* r = wp;
        wp += (bytes + 511) & ~(size_t)511;
        return r;
    };
    float* X      = (float*)alloc((size_t)N * 128 * 4);
    float* Y      = (float*)alloc((size_t)N * 128 * 4);
    int2*  csr    = (int2*)alloc((size_t)E * 8);
    int*   row    = (int*)alloc((size_t)(N + 1) * 4);
    int*   cursor = (int*)alloc((size_t)N * 4);
    int*   indeg  = (int*)alloc((size_t)N * 4);
    int*   outdeg = (int*)alloc((size_t)N * 4);
    float* onorm  = (float*)alloc((size_t)N * 4);
    float* inorm  = (float*)alloc((size_t)N * 4);
    int*   bsum   = (int*)alloc(4096);
    int*   boff   = (int*)alloc(4096);

    hipMemsetAsync(indeg,  0, (size_t)N * 4, stream);
    hipMemsetAsync(outdeg, 0, (size_t)N * 4, stream);
    hipMemsetAsync(cursor, 0, (size_t)N * 4, stream);

    const int eb = (E + 255) / 256;
    const int nb = (N + 255) / 256;

    k_degrees<<<eb, 256, 0, stream>>>(src, dst, outdeg, indeg, E);
    k_norms<<<nb, 256, 0, stream>>>(outdeg, indeg, onorm, inorm, N);
    k_scan_block<<<nb, 256, 0, stream>>>(indeg, row, bsum, N);
    k_scan_bsum<<<1, 512, 0, stream>>>(bsum, boff, nb);
    k_finalize_rows<<<nb, 256, 0, stream>>>(row, boff, N, E);
    k_fill<<<eb, 256, 0, stream>>>(src, dst, ew, onorm, row, cursor, csr, E);

    const int ab = (N + 3) / 4;              // 4 nodes (waves) per block
    const int gb = (N + 127) / 128;          // GEMM row tiles

    // layer 0
    k_agg128<<<ab, 256, 0, stream>>>(feat, row, csr, inorm, Y, N);
    k_gemm<128, 8, true, true><<<gb, 256, 0, stream>>>(Y, W0, b0, X, N);
    // layer 1
    k_agg128<<<ab, 256, 0, stream>>>(X, row, csr, inorm, Y, N);
    k_gemm<128, 8, true, true><<<gb, 256, 0, stream>>>(Y, W1, b1, X, N);
    // layer 2: GEMM first (128 -> 64), then aggregate + bias into d_out
    k_gemm<64, 4, false, false><<<gb, 256, 0, stream>>>(X, W2, nullptr, Y, N);
    k_agg64<<<ab, 256, 0, stream>>>(Y, row, csr, inorm, b2, out, N);
}

// Round 3
// 621.153 us; speedup vs baseline: 1.4076x; 1.1027x over previous
//
#include <hip/hip_runtime.h>
#include <cstddef>
#include <cstdint>

typedef float f4 __attribute__((ext_vector_type(4)));
typedef unsigned long long u64;
typedef unsigned long long u64x2 __attribute__((ext_vector_type(2)));

__device__ __forceinline__ int xcc_id() {
    // s_getreg_b32 hwreg(HW_REG_XCC_ID): id=20, offset=0, size=32
    return __builtin_amdgcn_s_getreg((31 << 11) | 20) & 7;
}

#define WG_ATOMIC_ADD(p, v) \
    __hip_atomic_fetch_add((p), (v), __ATOMIC_RELAXED, __HIP_MEMORY_SCOPE_WORKGROUP)

// ---------------------------------------------------------------------------
// GraphConv x3 (DGL norm='both', per-edge weight)
//   coef[e] = ew[e] * out_norm[src[e]]   (layer-independent, fused into CSR)
// CSR build: per-XCD L2-local histograms (workgroup-scope atomics) + rank,
// then atomic-free scatter.
// ---------------------------------------------------------------------------

// outdeg/indeg into per-XCD replicas; rank[e] = (xcd<<24) | local_rank
__global__ void __launch_bounds__(256)
k_hist(const int* __restrict__ src, const int* __restrict__ dst,
       int* __restrict__ od_r, int* __restrict__ id_r,
       int* __restrict__ rank, int N, int E) {
    const int x = xcc_id();
    int* od = od_r + (size_t)x * N;
    int* id = id_r + (size_t)x * N;
    const int tag = x << 24;
    const int i0 = (blockIdx.x * 256 + threadIdx.x) * 4;
    if (i0 + 4 <= E) {
        const int4 s = *(const int4*)&src[i0];
        const int4 d = *(const int4*)&dst[i0];
        WG_ATOMIC_ADD(&od[s.x], 1);
        WG_ATOMIC_ADD(&od[s.y], 1);
        WG_ATOMIC_ADD(&od[s.z], 1);
        WG_ATOMIC_ADD(&od[s.w], 1);
        int4 r;
        r.x = tag | WG_ATOMIC_ADD(&id[d.x], 1);
        r.y = tag | WG_ATOMIC_ADD(&id[d.y], 1);
        r.z = tag | WG_ATOMIC_ADD(&id[d.z], 1);
        r.w = tag | WG_ATOMIC_ADD(&id[d.w], 1);
        *(int4*)&rank[i0] = r;
    } else {
        for (int i = i0; i < E; ++i) {
            WG_ATOMIC_ADD(&od[src[i]], 1);
            rank[i] = tag | WG_ATOMIC_ADD(&id[dst[i]], 1);
        }
    }
}

// per node: total degrees, norms, per-XCD exclusive prefix of indeg replicas
__global__ void __launch_bounds__(256)
k_reduce(const int* __restrict__ od_r, const int* __restrict__ id_r,
         float* __restrict__ onorm, float* __restrict__ inorm,
         int* __restrict__ indeg, int* __restrict__ xp, int N) {
    const int i = blockIdx.x * blockDim.x + threadIdx.x;
    if (i >= N) return;
    int so = 0, si = 0;
    int pref[8];
    #pragma unroll
    for (int x = 0; x < 8; ++x) {
        pref[x] = si;
        si += id_r[(size_t)x * N + i];
        so += od_r[(size_t)x * N + i];
    }
    indeg[i] = si;
    onorm[i] = rsqrtf((float)(so < 1 ? 1 : so));
    inorm[i] = rsqrtf((float)(si < 1 ? 1 : si));
    #pragma unroll
    for (int x = 0; x < 8; ++x) xp[(size_t)x * N + i] = pref[x];
}

__global__ void k_scan_block(const int* __restrict__ in, int* __restrict__ out,
                             int* __restrict__ bsum, int N) {
    __shared__ int s[256];
    const int t = threadIdx.x;
    const int i = blockIdx.x * 256 + t;
    const int v = (i < N) ? in[i] : 0;
    s[t] = v;
    __syncthreads();
    for (int off = 1; off < 256; off <<= 1) {
        int x = (t >= off) ? s[t - off] : 0;
        __syncthreads();
        s[t] += x;
        __syncthreads();
    }
    if (i < N) out[i] = s[t] - v;
    if (t == 255) bsum[blockIdx.x] = s[255];
}

__global__ void k_scan_bsum(const int* __restrict__ bsum, int* __restrict__ boff, int nb) {
    __shared__ int s[512];
    const int t = threadIdx.x;
    const int v = (t < nb) ? bsum[t] : 0;
    s[t] = v;
    __syncthreads();
    for (int off = 1; off < 512; off <<= 1) {
        int x = (t >= off) ? s[t - off] : 0;
        __syncthreads();
        s[t] += x;
        __syncthreads();
    }
    if (t < nb) boff[t] = s[t] - v;
}

// row final; fold row into every xp replica so fill needs one gather
__global__ void k_finalize(int* __restrict__ row, const int* __restrict__ boff,
                           int* __restrict__ xp, int N, int E) {
    const int i = blockIdx.x * blockDim.x + threadIdx.x;
    if (i < N) {
        const int r = row[i] + boff[i >> 8];
        row[i] = r;
        #pragma unroll
        for (int x = 0; x < 8; ++x) xp[(size_t)x * N + i] += r;
    }
    if (i == 0) row[N] = E;
}

// atomic-free scatter: csr[pos] = {src, bits(ew*onorm[src])}
__global__ void __launch_bounds__(256)
k_fill(const int* __restrict__ src, const int* __restrict__ dst,
       const float* __restrict__ ew, const float* __restrict__ onorm,
       const int* __restrict__ rank, const int* __restrict__ xp,
       int2* __restrict__ csr, int N, int E) {
    const int i0 = (blockIdx.x * 256 + threadIdx.x) * 4;
    if (i0 + 4 <= E) {
        const int4 s  = *(const int4*)&src[i0];
        const int4 d  = *(const int4*)&dst[i0];
        const f4   w  = *(const f4*)&ew[i0];
        const int4 rk = *(const int4*)&rank[i0];
        const int ss[4] = {s.x, s.y, s.z, s.w};
        const int dd[4] = {d.x, d.y, d.z, d.w};
        const float ww[4] = {w.x, w.y, w.z, w.w};
        const int rr[4] = {rk.x, rk.y, rk.z, rk.w};
        #pragma unroll
        for (int j = 0; j < 4; ++j) {
            const int x = ((unsigned)rr[j]) >> 24;
            const int r = rr[j] & 0xFFFFFF;
            const int pos = xp[(size_t)x * N + dd[j]] + r;
            const float c = ww[j] * onorm[ss[j]];
            const u64 v = ((u64)(unsigned)__float_as_int(c) << 32) | (unsigned)ss[j];
            *(u64*)&csr[pos] = v;
        }
    } else {
        for (int i = i0; i < E; ++i) {
            const int x = ((unsigned)rank[i]) >> 24;
            const int r = rank[i] & 0xFFFFFF;
            const int pos = xp[(size_t)x * N + dst[i]] + r;
            const float c = ew[i] * onorm[src[i]];
            const u64 v = ((u64)(unsigned)__float_as_int(c) << 32) | (unsigned)src[i];
            *(u64*)&csr[pos] = v;
        }
    }
}

// one wave per node, width 128: halves own 4-edge chunks, 4 gathers in flight
__global__ void __launch_bounds__(256)
k_agg128(const float* __restrict__ h, const int* __restrict__ row,
         const int2* __restrict__ csr, const float* __restrict__ inorm,
         float* __restrict__ out, int N) {
    const int node = (int)((blockIdx.x * blockDim.x + threadIdx.x) >> 6);
    if (node >= N) return;
    const int lane = threadIdx.x & 63;
    const int half = lane >> 5;
    const int col = (lane & 31) * 4;
    int p = row[node];
    const int e = row[node + 1];
    f4 acc = {0.f, 0.f, 0.f, 0.f};
    for (; p + 8 <= e; p += 8) {
        const int b = p + 4 * half;
        const u64x2 ca = *(const u64x2*)&csr[b];
        const u64x2 cb = *(const u64x2*)&csr[b + 2];
        const f4 v0 = *(const f4*)(h + (size_t)(int)ca.x * 128 + col);
        const f4 v1 = *(const f4*)(h + (size_t)(int)ca.y * 128 + col);
        const f4 v2 = *(const f4*)(h + (size_t)(int)cb.x * 128 + col);
        const f4 v3 = *(const f4*)(h + (size_t)(int)cb.y * 128 + col);
        const float w0 = __int_as_float((int)(ca.x >> 32));
        const float w1 = __int_as_float((int)(ca.y >> 32));
        const float w2 = __int_as_float((int)(cb.x >> 32));
        const float w3 = __int_as_float((int)(cb.y >> 32));
        acc.x = fmaf(w0, v0.x, acc.x); acc.y = fmaf(w0, v0.y, acc.y);
        acc.z = fmaf(w0, v0.z, acc.z); acc.w = fmaf(w0, v0.w, acc.w);
        acc.x = fmaf(w1, v1.x, acc.x); acc.y = fmaf(w1, v1.y, acc.y);
        acc.z = fmaf(w1, v1.z, acc.z); acc.w = fmaf(w1, v1.w, acc.w);
        acc.x = fmaf(w2, v2.x, acc.x); acc.y = fmaf(w2, v2.y, acc.y);
        acc.z = fmaf(w2, v2.z, acc.z); acc.w = fmaf(w2, v2.w, acc.w);
        acc.x = fmaf(w3, v3.x, acc.x); acc.y = fmaf(w3, v3.y, acc.y);
        acc.z = fmaf(w3, v3.z, acc.z); acc.w = fmaf(w3, v3.w, acc.w);
    }
    for (; p < e; p += 2) {
        const int q = p + half;
        if (q < e) {
            const u64 c = *(const u64*)&csr[q];
            const f4 v = *(const f4*)(h + (size_t)(int)c * 128 + col);
            const float w = __int_as_float((int)(c >> 32));
            acc.x = fmaf(w, v.x, acc.x); acc.y = fmaf(w, v.y, acc.y);
            acc.z = fmaf(w, v.z, acc.z); acc.w = fmaf(w, v.w, acc.w);
        }
    }
    acc.x += __shfl_xor(acc.x, 32);
    acc.y += __shfl_xor(acc.y, 32);
    acc.z += __shfl_xor(acc.z, 32);
    acc.w += __shfl_xor(acc.w, 32);
    if (half == 0) {
        const float nn = inorm[node];
        f4 r = {acc.x * nn, acc.y * nn, acc.z * nn, acc.w * nn};
        *(f4*)(out + (size_t)node * 128 + col) = r;
    }
}

// one wave per node, width 64: quarters own 4-edge chunks; fused bias, output
__global__ void __launch_bounds__(256)
k_agg64(const float* __restrict__ h, const int* __restrict__ row,
        const int2* __restrict__ csr, const float* __restrict__ inorm,
        const float* __restrict__ bias, float* __restrict__ out, int N) {
    const int node = (int)((blockIdx.x * blockDim.x + threadIdx.x) >> 6);
    if (node >= N) return;
    const int lane = threadIdx.x & 63;
    const int q = lane >> 4;
    const int col = (lane & 15) * 4;
    int p = row[node];
    const int e = row[node + 1];
    f4 acc = {0.f, 0.f, 0.f, 0.f};
    for (; p + 16 <= e; p += 16) {
        const int b = p + 4 * q;
        const u64x2 ca = *(const u64x2*)&csr[b];
        const u64x2 cb = *(const u64x2*)&csr[b + 2];
        const f4 v0 = *(const f4*)(h + (size_t)(int)ca.x * 64 + col);
        const f4 v1 = *(const f4*)(h + (size_t)(int)ca.y * 64 + col);
        const f4 v2 = *(const f4*)(h + (size_t)(int)cb.x * 64 + col);
        const f4 v3 = *(const f4*)(h + (size_t)(int)cb.y * 64 + col);
        const float w0 = __int_as_float((int)(ca.x >> 32));
        const float w1 = __int_as_float((int)(ca.y >> 32));
        const float w2 = __int_as_float((int)(cb.x >> 32));
        const float w3 = __int_as_float((int)(cb.y >> 32));
        acc.x = fmaf(w0, v0.x, acc.x); acc.y = fmaf(w0, v0.y, acc.y);
        acc.z = fmaf(w0, v0.z, acc.z); acc.w = fmaf(w0, v0.w, acc.w);
        acc.x = fmaf(w1, v1.x, acc.x); acc.y = fmaf(w1, v1.y, acc.y);
        acc.z = fmaf(w1, v1.z, acc.z); acc.w = fmaf(w1, v1.w, acc.w);
        acc.x = fmaf(w2, v2.x, acc.x); acc.y = fmaf(w2, v2.y, acc.y);
        acc.z = fmaf(w2, v2.z, acc.z); acc.w = fmaf(w2, v2.w, acc.w);
        acc.x = fmaf(w3, v3.x, acc.x); acc.y = fmaf(w3, v3.y, acc.y);
        acc.z = fmaf(w3, v3.z, acc.z); acc.w = fmaf(w3, v3.w, acc.w);
    }
    for (; p < e; p += 4) {
        const int idx = p + q;
        if (idx < e) {
            const u64 c = *(const u64*)&csr[idx];
            const f4 v = *(const f4*)(h + (size_t)(int)c * 64 + col);
            const float w = __int_as_float((int)(c >> 32));
            acc.x = fmaf(w, v.x, acc.x); acc.y = fmaf(w, v.y, acc.y);
            acc.z = fmaf(w, v.z, acc.z); acc.w = fmaf(w, v.w, acc.w);
        }
    }
    acc.x += __shfl_xor(acc.x, 16); acc.y += __shfl_xor(acc.y, 16);
    acc.z += __shfl_xor(acc.z, 16); acc.w += __shfl_xor(acc.w, 16);
    acc.x += __shfl_xor(acc.x, 32); acc.y += __shfl_xor(acc.y, 32);
    acc.z += __shfl_xor(acc.z, 32); acc.w += __shfl_xor(acc.w, 32);
    if (lane < 16) {
        const float nn = inorm[node];
        const f4 bv = *(const f4*)(bias + col);
        f4 r = {acc.x * nn + bv.x, acc.y * nn + bv.y,
                acc.z * nn + bv.z, acc.w * nn + bv.w};
        *(f4*)(out + (size_t)node * 64 + col) = r;
    }
}

// C[N x BN] = A[N x 128] @ W[128 x BN] (+bias, +relu)
template <int BN, int TN, bool RELU, bool BIAS>
__global__ void __launch_bounds__(256)
k_gemm(const float* __restrict__ A, const float* __restrict__ W,
       const float* __restrict__ bias, float* __restrict__ C, int N) {
    __shared__ float As[32][132];
    __shared__ float Ws[32][BN];
    const int t   = threadIdx.x;
    const int bm0 = blockIdx.x * 128;
    const int tx  = t & 15;
    const int ty  = t >> 4;

    float acc[8][TN];
    #pragma unroll
    for (int i = 0; i < 8; ++i)
        #pragma unroll
        for (int j = 0; j < TN; ++j) acc[i][j] = 0.f;

    for (int kt = 0; kt < 4; ++kt) {
        __syncthreads();
        #pragma unroll
        for (int r = 0; r < 4; ++r) {
            const int idx = r * 256 + t;
            const int m = idx >> 3, f = idx & 7;
            const int gm = bm0 + m;
            f4 v = {0.f, 0.f, 0.f, 0.f};
            if (gm < N) v = *(const f4*)(A + (size_t)gm * 128 + kt * 32 + f * 4);
            As[f * 4 + 0][m] = v.x;
            As[f * 4 + 1][m] = v.y;
            As[f * 4 + 2][m] = v.z;
            As[f * 4 + 3][m] = v.w;
        }
        #pragma unroll
        for (int r = 0; r < (BN == 128 ? 4 : 2); ++r) {
            const int idx = r * 256 + t;
            const int kk = idx / (BN / 4), f = idx % (BN / 4);
            *(f4*)&Ws[kk][f * 4] = *(const f4*)(W + (size_t)(kt * 32 + kk) * BN + f * 4);
        }
        __syncthreads();
        #pragma unroll
        for (int k = 0; k < 32; ++k) {
            const f4 a0 = *(const f4*)&As[k][ty * 8];
            const f4 a1 = *(const f4*)&As[k][ty * 8 + 4];
            const float a[8] = {a0.x, a0.y, a0.z, a0.w, a1.x, a1.y, a1.z, a1.w};
            float b[TN];
            *(f4*)&b[0] = *(const f4*)&Ws[k][tx * TN];
            if (TN == 8) *(f4*)&b[4] = *(const f4*)&Ws[k][tx * TN + 4];
            #pragma unroll
            for (int i = 0; i < 8; ++i)
                #pragma unroll
                for (int j = 0; j < TN; ++j)
                    acc[i][j] = fmaf(a[i], b[j], acc[i][j]);
        }
    }

    float bb[TN];
    #pragma unroll
    for (int j = 0; j < TN; ++j) bb[j] = BIAS ? bias[tx * TN + j] : 0.f;

    #pragma unroll
    for (int i = 0; i < 8; ++i) {
        const int gm = bm0 + ty * 8 + i;
        if (gm < N) {
            #pragma unroll
            for (int j0 = 0; j0 < TN; j0 += 4) {
                f4 v = {acc[i][j0 + 0] + bb[j0 + 0], acc[i][j0 + 1] + bb[j0 + 1],
                        acc[i][j0 + 2] + bb[j0 + 2], acc[i][j0 + 3] + bb[j0 + 3]};
                if (RELU) {
                    v.x = v.x > 0.f ? v.x : 0.f;
                    v.y = v.y > 0.f ? v.y : 0.f;
                    v.z = v.z > 0.f ? v.z : 0.f;
                    v.w = v.w > 0.f ? v.w : 0.f;
                }
                *(f4*)(C + (size_t)gm * BN + tx * TN + j0) = v;
            }
        }
    }
}

extern "C" void kernel_launch(void* const* d_in, const int* in_sizes, int n_in,
                              void* d_out, int out_size, void* d_ws, size_t ws_size,
                              hipStream_t stream) {
    const float* feat = (const float*)d_in[0];
    const int*   src  = (const int*)d_in[1];
    const int*   dst  = (const int*)d_in[2];
    const float* ew   = (const float*)d_in[3];
    const float* W0   = (const float*)d_in[4];
    const float* b0   = (const float*)d_in[5];
    const float* W1   = (const float*)d_in[6];
    const float* b1   = (const float*)d_in[7];
    const float* W2   = (const float*)d_in[8];
    const float* b2   = (const float*)d_in[9];
    float* out = (float*)d_out;

    const int N = in_sizes[0] / 128;
    const int E = in_sizes[1];

    uint8_t* wp = (uint8_t*)d_ws;
    auto alloc = [&](size_t bytes) {
        uint8_t* r = wp;
        wp += (bytes + 511) & ~(size_t)511;
        return r;
    };
    float* X     = (float*)alloc((size_t)N * 128 * 4);   // aliases: rank, xp
    float* Y     = (float*)alloc((size_t)N * 128 * 4);   // aliases: od_r, id_r
    int2*  csr   = (int2*)alloc((size_t)E * 8);
    int*   row   = (int*)alloc((size_t)(N + 1) * 4);
    int*   indeg = (int*)alloc((size_t)N * 4);
    float* onorm = (float*)alloc((size_t)N * 4);
    float* inorm = (float*)alloc((size_t)N * 4);
    int*   bsum  = (int*)alloc(4096);
    int*   boff  = (int*)alloc(4096);

    // prep-phase aliases (dead before X/Y are first written)
    int* rank = (int*)X;                                          // E*4
    int* xp   = (int*)((uint8_t*)X + (((size_t)E * 4 + 511) & ~(size_t)511)); // 8*N*4
    int* od_r = (int*)Y;                                          // 8*N*4
    int* id_r = (int*)((uint8_t*)Y + (((size_t)N * 32 + 511) & ~(size_t)511)); // 8*N*4

    hipMemsetAsync(od_r, 0, (size_t)N * 32, stream);
    hipMemsetAsync(id_r, 0, (size_t)N * 32, stream);

    const int e4b = ((E + 3) / 4 + 255) / 256;   // 4 edges/thread kernels
    const int nb  = (N + 255) / 256;

    k_hist<<<e4b, 256, 0, stream>>>(src, dst, od_r, id_r, rank, N, E);
    k_reduce<<<nb, 256, 0, stream>>>(od_r, id_r, onorm, inorm, indeg, xp, N);
    k_scan_block<<<nb, 256, 0, stream>>>(indeg, row, bsum, N);
    k_scan_bsum<<<1, 512, 0, stream>>>(bsum, boff, nb);
    k_finalize<<<nb, 256, 0, stream>>>(row, boff, xp, N, E);
    k_fill<<<e4b, 256, 0, stream>>>(src, dst, ew, onorm, rank, xp, csr, N, E);

    const int ab = (N + 3) / 4;
    const int gb = (N + 127) / 128;

    // layer 0
    k_agg128<<<ab, 256, 0, stream>>>(feat, row, csr, inorm, Y, N);
    k_gemm<128, 8, true, true><<<gb, 256, 0, stream>>>(Y, W0, b0, X, N);
    // layer 1
    k_agg128<<<ab, 256, 0, stream>>>(X, row, csr, inorm, Y, N);
    k_gemm<128, 8, true, true><<<gb, 256, 0, stream>>>(Y, W1, b1, X, N);
    // layer 2: GEMM first (128 -> 64), then aggregate + bias into d_out
    k_gemm<64, 4, false, false><<<gb, 256, 0, stream>>>(X, W2, nullptr, Y, N);
    k_agg64<<<ab, 256, 0, stream>>>(Y, row, csr, inorm, b2, out, N);
}

// Round 4
// 513.354 us; speedup vs baseline: 1.7032x; 1.2100x over previous
//
#include <hip/hip_runtime.h>
#include <cstddef>
#include <cstdint>

typedef float f4 __attribute__((ext_vector_type(4)));
typedef unsigned long long u64;
typedef unsigned long long u64x2 __attribute__((ext_vector_type(2)));
typedef unsigned short u16;

// ---------------------------------------------------------------------------
// GraphConv x3 (DGL norm='both', per-edge weight)
//   coef[e] = ew[e] * out_norm[src[e]]  (layer-independent, fused into CSR)
// CSR build: two-level counting sort (LDS atomics only, no fabric atomics).
//   buckets = key>>8 (256 nodes each), NB = ceil(N/256) = 391 for N=100k
//   P1 blocks own 4096 edges; in-block LDS hist + rank (u16)
// ---------------------------------------------------------------------------

#define EPB 4096    // edges per P1/P3 block

// P1: per-block coarse histograms (dst and src) + in-block ranks
__global__ void __launch_bounds__(256)
k_p1(const int* __restrict__ src, const int* __restrict__ dst,
     u16* __restrict__ lrank_s, u16* __restrict__ lrank_d,
     int* __restrict__ bh_s, int* __restrict__ bh_d, int NB, int E) {
    __shared__ int hs[512], hd[512];
    const int t = threadIdx.x, b = blockIdx.x;
    for (int i = t; i < NB; i += 256) { hs[i] = 0; hd[i] = 0; }
    __syncthreads();
    const int e0 = b * EPB;
    #pragma unroll
    for (int j = 0; j < 4; ++j) {
        const int e = e0 + j * 1024 + t * 4;
        if (e + 4 <= E) {
            const int4 d = *(const int4*)&dst[e];
            const int4 s = *(const int4*)&src[e];
            unsigned rd0 = atomicAdd(&hd[d.x >> 8], 1);
            unsigned rd1 = atomicAdd(&hd[d.y >> 8], 1);
            unsigned rd2 = atomicAdd(&hd[d.z >> 8], 1);
            unsigned rd3 = atomicAdd(&hd[d.w >> 8], 1);
            unsigned rs0 = atomicAdd(&hs[s.x >> 8], 1);
            unsigned rs1 = atomicAdd(&hs[s.y >> 8], 1);
            unsigned rs2 = atomicAdd(&hs[s.z >> 8], 1);
            unsigned rs3 = atomicAdd(&hs[s.w >> 8], 1);
            *(uint2*)&lrank_d[e] = make_uint2(rd0 | (rd1 << 16), rd2 | (rd3 << 16));
            *(uint2*)&lrank_s[e] = make_uint2(rs0 | (rs1 << 16), rs2 | (rs3 << 16));
        } else {
            for (int k = e; k < E && k < e + 4; ++k) {
                lrank_d[k] = (u16)atomicAdd(&hd[dst[k] >> 8], 1);
                lrank_s[k] = (u16)atomicAdd(&hs[src[k] >> 8], 1);
            }
        }
    }
    __syncthreads();
    for (int i = t; i < NB; i += 256) {
        bh_d[b * NB + i] = hd[i];
        bh_s[b * NB + i] = hs[i];
    }
}

// P2: per bucket, exclusive scan over blocks (in-place) + bucket totals
__global__ void __launch_bounds__(512)
k_p2(int* __restrict__ bh_d, int* __restrict__ bh_s,
     int* __restrict__ cb_d, int* __restrict__ cb_s, int NB, int B1) {
    __shared__ int s[512];
    const int B = blockIdx.x, i = threadIdx.x;
    int* bh = blockIdx.y ? bh_s : bh_d;
    int* cb = blockIdx.y ? cb_s : cb_d;
    const int v = (i < B1) ? bh[i * NB + B] : 0;
    s[i] = v;
    __syncthreads();
    for (int off = 1; off < 512; off <<= 1) {
        const int x = (i >= off) ? s[i - off] : 0;
        __syncthreads();
        s[i] += x;
        __syncthreads();
    }
    if (i < B1) bh[i * NB + B] = s[i] - v;
    if (i == 511) cb[B] = s[511];
}

// P2b: exclusive scan of bucket totals -> bucket bases; row[N] = E
__global__ void __launch_bounds__(512)
k_p2b(const int* __restrict__ cb_d, const int* __restrict__ cb_s,
      int* __restrict__ bktb_d, int* __restrict__ bktb_s,
      int* __restrict__ row, int NB, int N, int E) {
    __shared__ int s[512];
    const int t = threadIdx.x;
    int v = (t < NB) ? cb_d[t] : 0;
    s[t] = v;
    __syncthreads();
    for (int off = 1; off < 512; off <<= 1) {
        const int x = (t >= off) ? s[t - off] : 0;
        __syncthreads();
        s[t] += x;
        __syncthreads();
    }
    if (t < NB) bktb_d[t] = s[t] - v;
    __syncthreads();
    v = (t < NB) ? cb_s[t] : 0;
    s[t] = v;
    __syncthreads();
    for (int off = 1; off < 512; off <<= 1) {
        const int x = (t >= off) ? s[t - off] : 0;
        __syncthreads();
        s[t] += x;
        __syncthreads();
    }
    if (t < NB) bktb_s[t] = s[t] - v;
    if (t == 0) row[N] = E;
}

// P3: scatter edges into dst-bucket order (tdst + (src,ew) payload) and
//     srcs into src-bucket order (tsrc). Same chunking as P1.
__global__ void __launch_bounds__(256)
k_p3(const int* __restrict__ src, const int* __restrict__ dst,
     const float* __restrict__ ew,
     const u16* __restrict__ lrank_s, const u16* __restrict__ lrank_d,
     const int* __restrict__ bh_s, const int* __restrict__ bh_d,
     const int* __restrict__ bktb_s, const int* __restrict__ bktb_d,
     int* __restrict__ tdst, int2* __restrict__ tsw, int* __restrict__ tsrc,
     int NB, int E) {
    const int t = threadIdx.x, b = blockIdx.x;
    const int e0 = b * EPB;
    #pragma unroll
    for (int j = 0; j < 4; ++j) {
        const int e = e0 + j * 1024 + t * 4;
        if (e + 4 <= E) {
            const int4 d = *(const int4*)&dst[e];
            const int4 s = *(const int4*)&src[e];
            const f4   w = *(const f4*)&ew[e];
            const uint2 rd = *(const uint2*)&lrank_d[e];
            const uint2 rs = *(const uint2*)&lrank_s[e];
            const int dd[4] = {d.x, d.y, d.z, d.w};
            const int ss[4] = {s.x, s.y, s.z, s.w};
            const float ww[4] = {w.x, w.y, w.z, w.w};
            const int rrd[4] = {(int)(rd.x & 0xFFFF), (int)(rd.x >> 16),
                                (int)(rd.y & 0xFFFF), (int)(rd.y >> 16)};
            const int rrs[4] = {(int)(rs.x & 0xFFFF), (int)(rs.x >> 16),
                                (int)(rs.y & 0xFFFF), (int)(rs.y >> 16)};
            #pragma unroll
            for (int k = 0; k < 4; ++k) {
                const int Bd = dd[k] >> 8;
                const int posd = bktb_d[Bd] + bh_d[b * NB + Bd] + rrd[k];
                tdst[posd] = dd[k];
                tsw[posd] = make_int2(ss[k], __float_as_int(ww[k]));
                const int Bs = ss[k] >> 8;
                const int poss = bktb_s[Bs] + bh_s[b * NB + Bs] + rrs[k];
                tsrc[poss] = ss[k];
            }
        } else {
            for (int k = e; k < E && k < e + 4; ++k) {
                const int dv = dst[k], sv = src[k];
                const int Bd = dv >> 8;
                const int posd = bktb_d[Bd] + bh_d[b * NB + Bd] + (int)lrank_d[k];
                tdst[posd] = dv;
                tsw[posd] = make_int2(sv, __float_as_int(ew[k]));
                const int Bs = sv >> 8;
                const int poss = bktb_s[Bs] + bh_s[b * NB + Bs] + (int)lrank_s[k];
                tsrc[poss] = sv;
            }
        }
    }
}

// P4s: per src-bucket count -> onorm
__global__ void __launch_bounds__(256)
k_p4s(const int* __restrict__ tsrc, const int* __restrict__ bktb_s,
      const int* __restrict__ cb_s, float* __restrict__ onorm, int NB, int N) {
    __shared__ int cnt[256];
    const int B = blockIdx.x, t = threadIdx.x;
    cnt[t] = 0;
    __syncthreads();
    const int base = bktb_s[B], cb = cb_s[B];
    for (int i = t; i < cb; i += 256) atomicAdd(&cnt[tsrc[base + i] & 255], 1);
    __syncthreads();
    const int n = (B << 8) + t;
    if (n < N) {
        const int c = cnt[t];
        onorm[n] = rsqrtf((float)(c < 1 ? 1 : c));
    }
}

// P4d: per dst-bucket count -> row/inorm, then rank-scatter csr entries
__global__ void __launch_bounds__(256)
k_p4d(const int* __restrict__ tdst, const int2* __restrict__ tsw,
      const int* __restrict__ bktb_d, const int* __restrict__ cb_d,
      const float* __restrict__ onorm, int* __restrict__ row,
      float* __restrict__ inorm, int2* __restrict__ csr, int NB, int N) {
    __shared__ int cnt[256], cnt2[256], lrow[256], sc[256];
    const int B = blockIdx.x, t = threadIdx.x;
    cnt[t] = 0; cnt2[t] = 0;
    __syncthreads();
    const int base = bktb_d[B], cb = cb_d[B];
    for (int i = t; i < cb; i += 256) atomicAdd(&cnt[tdst[base + i] & 255], 1);
    __syncthreads();
    const int v = cnt[t];
    sc[t] = v;
    __syncthreads();
    for (int off = 1; off < 256; off <<= 1) {
        const int x = (t >= off) ? sc[t - off] : 0;
        __syncthreads();
        sc[t] += x;
        __syncthreads();
    }
    const int excl = sc[t] - v;
    lrow[t] = excl;
    const int n = (B << 8) + t;
    if (n < N) {
        row[n] = base + excl;
        inorm[n] = rsqrtf((float)(v < 1 ? 1 : v));
    }
    __syncthreads();
    for (int i = t; i < cb; i += 256) {
        const int d = tdst[base + i] & 255;
        const int2 sw = tsw[base + i];
        const int r = atomicAdd(&cnt2[d], 1);
        const float coef = __int_as_float(sw.y) * onorm[sw.x];
        csr[base + lrow[d] + r] = make_int2(sw.x, __float_as_int(coef));
    }
}

// one wave per node, width 128: halves own 4-edge chunks, 4 gathers in flight
__global__ void __launch_bounds__(256)
k_agg128(const float* __restrict__ h, const int* __restrict__ row,
         const int2* __restrict__ csr, const float* __restrict__ inorm,
         float* __restrict__ out, int N) {
    const int node = (int)((blockIdx.x * blockDim.x + threadIdx.x) >> 6);
    if (node >= N) return;
    const int lane = threadIdx.x & 63;
    const int half = lane >> 5;
    const int col = (lane & 31) * 4;
    int p = row[node];
    const int e = row[node + 1];
    f4 acc = {0.f, 0.f, 0.f, 0.f};
    for (; p + 8 <= e; p += 8) {
        const int b = p + 4 * half;
        const u64x2 ca = *(const u64x2*)&csr[b];
        const u64x2 cb = *(const u64x2*)&csr[b + 2];
        const f4 v0 = *(const f4*)(h + (size_t)(int)ca.x * 128 + col);
        const f4 v1 = *(const f4*)(h + (size_t)(int)ca.y * 128 + col);
        const f4 v2 = *(const f4*)(h + (size_t)(int)cb.x * 128 + col);
        const f4 v3 = *(const f4*)(h + (size_t)(int)cb.y * 128 + col);
        const float w0 = __int_as_float((int)(ca.x >> 32));
        const float w1 = __int_as_float((int)(ca.y >> 32));
        const float w2 = __int_as_float((int)(cb.x >> 32));
        const float w3 = __int_as_float((int)(cb.y >> 32));
        acc.x = fmaf(w0, v0.x, acc.x); acc.y = fmaf(w0, v0.y, acc.y);
        acc.z = fmaf(w0, v0.z, acc.z); acc.w = fmaf(w0, v0.w, acc.w);
        acc.x = fmaf(w1, v1.x, acc.x); acc.y = fmaf(w1, v1.y, acc.y);
        acc.z = fmaf(w1, v1.z, acc.z); acc.w = fmaf(w1, v1.w, acc.w);
        acc.x = fmaf(w2, v2.x, acc.x); acc.y = fmaf(w2, v2.y, acc.y);
        acc.z = fmaf(w2, v2.z, acc.z); acc.w = fmaf(w2, v2.w, acc.w);
        acc.x = fmaf(w3, v3.x, acc.x); acc.y = fmaf(w3, v3.y, acc.y);
        acc.z = fmaf(w3, v3.z, acc.z); acc.w = fmaf(w3, v3.w, acc.w);
    }
    for (; p < e; p += 2) {
        const int q = p + half;
        if (q < e) {
            const u64 c = *(const u64*)&csr[q];
            const f4 v = *(const f4*)(h + (size_t)(int)c * 128 + col);
            const float w = __int_as_float((int)(c >> 32));
            acc.x = fmaf(w, v.x, acc.x); acc.y = fmaf(w, v.y, acc.y);
            acc.z = fmaf(w, v.z, acc.z); acc.w = fmaf(w, v.w, acc.w);
        }
    }
    acc.x += __shfl_xor(acc.x, 32);
    acc.y += __shfl_xor(acc.y, 32);
    acc.z += __shfl_xor(acc.z, 32);
    acc.w += __shfl_xor(acc.w, 32);
    if (half == 0) {
        const float nn = inorm[node];
        f4 r = {acc.x * nn, acc.y * nn, acc.z * nn, acc.w * nn};
        *(f4*)(out + (size_t)node * 128 + col) = r;
    }
}

// one wave per node, width 64: quarters own 4-edge chunks; fused bias, output
__global__ void __launch_bounds__(256)
k_agg64(const float* __restrict__ h, const int* __restrict__ row,
        const int2* __restrict__ csr, const float* __restrict__ inorm,
        const float* __restrict__ bias, float* __restrict__ out, int N) {
    const int node = (int)((blockIdx.x * blockDim.x + threadIdx.x) >> 6);
    if (node >= N) return;
    const int lane = threadIdx.x & 63;
    const int q = lane >> 4;
    const int col = (lane & 15) * 4;
    int p = row[node];
    const int e = row[node + 1];
    f4 acc = {0.f, 0.f, 0.f, 0.f};
    for (; p + 16 <= e; p += 16) {
        const int b = p + 4 * q;
        const u64x2 ca = *(const u64x2*)&csr[b];
        const u64x2 cb = *(const u64x2*)&csr[b + 2];
        const f4 v0 = *(const f4*)(h + (size_t)(int)ca.x * 64 + col);
        const f4 v1 = *(const f4*)(h + (size_t)(int)ca.y * 64 + col);
        const f4 v2 = *(const f4*)(h + (size_t)(int)cb.x * 64 + col);
        const f4 v3 = *(const f4*)(h + (size_t)(int)cb.y * 64 + col);
        const float w0 = __int_as_float((int)(ca.x >> 32));
        const float w1 = __int_as_float((int)(ca.y >> 32));
        const float w2 = __int_as_float((int)(cb.x >> 32));
        const float w3 = __int_as_float((int)(cb.y >> 32));
        acc.x = fmaf(w0, v0.x, acc.x); acc.y = fmaf(w0, v0.y, acc.y);
        acc.z = fmaf(w0, v0.z, acc.z); acc.w = fmaf(w0, v0.w, acc.w);
        acc.x = fmaf(w1, v1.x, acc.x); acc.y = fmaf(w1, v1.y, acc.y);
        acc.z = fmaf(w1, v1.z, acc.z); acc.w = fmaf(w1, v1.w, acc.w);
        acc.x = fmaf(w2, v2.x, acc.x); acc.y = fmaf(w2, v2.y, acc.y);
        acc.z = fmaf(w2, v2.z, acc.z); acc.w = fmaf(w2, v2.w, acc.w);
        acc.x = fmaf(w3, v3.x, acc.x); acc.y = fmaf(w3, v3.y, acc.y);
        acc.z = fmaf(w3, v3.z, acc.z); acc.w = fmaf(w3, v3.w, acc.w);
    }
    for (; p < e; p += 4) {
        const int idx = p + q;
        if (idx < e) {
            const u64 c = *(const u64*)&csr[idx];
            const f4 v = *(const f4*)(h + (size_t)(int)c * 64 + col);
            const float w = __int_as_float((int)(c >> 32));
            acc.x = fmaf(w, v.x, acc.x); acc.y = fmaf(w, v.y, acc.y);
            acc.z = fmaf(w, v.z, acc.z); acc.w = fmaf(w, v.w, acc.w);
        }
    }
    acc.x += __shfl_xor(acc.x, 16); acc.y += __shfl_xor(acc.y, 16);
    acc.z += __shfl_xor(acc.z, 16); acc.w += __shfl_xor(acc.w, 16);
    acc.x += __shfl_xor(acc.x, 32); acc.y += __shfl_xor(acc.y, 32);
    acc.z += __shfl_xor(acc.z, 32); acc.w += __shfl_xor(acc.w, 32);
    if (lane < 16) {
        const float nn = inorm[node];
        const f4 bv = *(const f4*)(bias + col);
        f4 r = {acc.x * nn + bv.x, acc.y * nn + bv.y,
                acc.z * nn + bv.z, acc.w * nn + bv.w};
        *(f4*)(out + (size_t)node * 64 + col) = r;
    }
}

// C[N x BN] = A[N x 128] @ W[128 x BN] (+bias, +relu)
template <int BN, int TN, bool RELU, bool BIAS>
__global__ void __launch_bounds__(256)
k_gemm(const float* __restrict__ A, const float* __restrict__ W,
       const float* __restrict__ bias, float* __restrict__ C, int N) {
    __shared__ float As[32][132];
    __shared__ float Ws[32][BN];
    const int t   = threadIdx.x;
    const int bm0 = blockIdx.x * 128;
    const int tx  = t & 15;
    const int ty  = t >> 4;

    float acc[8][TN];
    #pragma unroll
    for (int i = 0; i < 8; ++i)
        #pragma unroll
        for (int j = 0; j < TN; ++j) acc[i][j] = 0.f;

    for (int kt = 0; kt < 4; ++kt) {
        __syncthreads();
        #pragma unroll
        for (int r = 0; r < 4; ++r) {
            const int idx = r * 256 + t;
            const int m = idx >> 3, f = idx & 7;
            const int gm = bm0 + m;
            f4 v = {0.f, 0.f, 0.f, 0.f};
            if (gm < N) v = *(const f4*)(A + (size_t)gm * 128 + kt * 32 + f * 4);
            As[f * 4 + 0][m] = v.x;
            As[f * 4 + 1][m] = v.y;
            As[f * 4 + 2][m] = v.z;
            As[f * 4 + 3][m] = v.w;
        }
        #pragma unroll
        for (int r = 0; r < (BN == 128 ? 4 : 2); ++r) {
            const int idx = r * 256 + t;
            const int kk = idx / (BN / 4), f = idx % (BN / 4);
            *(f4*)&Ws[kk][f * 4] = *(const f4*)(W + (size_t)(kt * 32 + kk) * BN + f * 4);
        }
        __syncthreads();
        #pragma unroll
        for (int k = 0; k < 32; ++k) {
            const f4 a0 = *(const f4*)&As[k][ty * 8];
            const f4 a1 = *(const f4*)&As[k][ty * 8 + 4];
            const float a[8] = {a0.x, a0.y, a0.z, a0.w, a1.x, a1.y, a1.z, a1.w};
            float b[TN];
            *(f4*)&b[0] = *(const f4*)&Ws[k][tx * TN];
            if (TN == 8) *(f4*)&b[4] = *(const f4*)&Ws[k][tx * TN + 4];
            #pragma unroll
            for (int i = 0; i < 8; ++i)
                #pragma unroll
                for (int j = 0; j < TN; ++j)
                    acc[i][j] = fmaf(a[i], b[j], acc[i][j]);
        }
    }

    float bb[TN];
    #pragma unroll
    for (int j = 0; j < TN; ++j) bb[j] = BIAS ? bias[tx * TN + j] : 0.f;

    #pragma unroll
    for (int i = 0; i < 8; ++i) {
        const int gm = bm0 + ty * 8 + i;
        if (gm < N) {
            #pragma unroll
            for (int j0 = 0; j0 < TN; j0 += 4) {
                f4 v = {acc[i][j0 + 0] + bb[j0 + 0], acc[i][j0 + 1] + bb[j0 + 1],
                        acc[i][j0 + 2] + bb[j0 + 2], acc[i][j0 + 3] + bb[j0 + 3]};
                if (RELU) {
                    v.x = v.x > 0.f ? v.x : 0.f;
                    v.y = v.y > 0.f ? v.y : 0.f;
                    v.z = v.z > 0.f ? v.z : 0.f;
                    v.w = v.w > 0.f ? v.w : 0.f;
                }
                *(f4*)(C + (size_t)gm * BN + tx * TN + j0) = v;
            }
        }
    }
}

extern "C" void kernel_launch(void* const* d_in, const int* in_sizes, int n_in,
                              void* d_out, int out_size, void* d_ws, size_t ws_size,
                              hipStream_t stream) {
    const float* feat = (const float*)d_in[0];
    const int*   src  = (const int*)d_in[1];
    const int*   dst  = (const int*)d_in[2];
    const float* ew   = (const float*)d_in[3];
    const float* W0   = (const float*)d_in[4];
    const float* b0   = (const float*)d_in[5];
    const float* W1   = (const float*)d_in[6];
    const float* b1   = (const float*)d_in[7];
    const float* W2   = (const float*)d_in[8];
    const float* b2   = (const float*)d_in[9];
    float* out = (float*)d_out;

    const int N = in_sizes[0] / 128;
    const int E = in_sizes[1];
    const int NB = (N + 255) / 256;      // coarse buckets (<=512)
    const int B1 = (E + EPB - 1) / EPB;  // P1/P3 blocks   (<=512)

    uint8_t* wp = (uint8_t*)d_ws;
    auto alloc = [&](size_t bytes) {
        uint8_t* r = wp;
        wp += (bytes + 511) & ~(size_t)511;
        return r;
    };
    float* X     = (float*)alloc((size_t)N * 128 * 4);
    float* Y     = (float*)alloc((size_t)N * 128 * 4);
    int2*  csr   = (int2*)alloc((size_t)E * 8);
    int*   row   = (int*)alloc((size_t)(N + 1) * 4);
    float* onorm = (float*)alloc((size_t)N * 4);
    float* inorm = (float*)alloc((size_t)N * 4);

    // prep-phase aliases inside X (dead before X first written by gemm0)
    uint8_t* xp = (uint8_t*)X;
    auto xalloc = [&](size_t bytes) {
        uint8_t* r = xp;
        xp += (bytes + 511) & ~(size_t)511;
        return r;
    };
    u16* lrank_d = (u16*)xalloc((size_t)E * 2);
    u16* lrank_s = (u16*)xalloc((size_t)E * 2);
    int* bh_d    = (int*)xalloc((size_t)B1 * NB * 4);
    int* bh_s    = (int*)xalloc((size_t)B1 * NB * 4);
    int* cb_d    = (int*)xalloc((size_t)NB * 4);
    int* cb_s    = (int*)xalloc((size_t)NB * 4);
    int* bktb_d  = (int*)xalloc((size_t)NB * 4);
    int* bktb_s  = (int*)xalloc((size_t)NB * 4);

    // prep-phase aliases inside Y (dead before Y first written by agg128 #1)
    uint8_t* yp = (uint8_t*)Y;
    auto yalloc = [&](size_t bytes) {
        uint8_t* r = yp;
        yp += (bytes + 511) & ~(size_t)511;
        return r;
    };
    int*  tdst = (int*)yalloc((size_t)E * 4);
    int2* tsw  = (int2*)yalloc((size_t)E * 8);
    int*  tsrc = (int*)yalloc((size_t)E * 4);

    // ---- CSR build (no fabric atomics) ----
    k_p1<<<B1, 256, 0, stream>>>(src, dst, lrank_s, lrank_d, bh_s, bh_d, NB, E);
    k_p2<<<dim3(NB, 2), 512, 0, stream>>>(bh_d, bh_s, cb_d, cb_s, NB, B1);
    k_p2b<<<1, 512, 0, stream>>>(cb_d, cb_s, bktb_d, bktb_s, row, NB, N, E);
    k_p3<<<B1, 256, 0, stream>>>(src, dst, ew, lrank_s, lrank_d, bh_s, bh_d,
                                 bktb_s, bktb_d, tdst, tsw, tsrc, NB, E);
    k_p4s<<<NB, 256, 0, stream>>>(tsrc, bktb_s, cb_s, onorm, NB, N);
    k_p4d<<<NB, 256, 0, stream>>>(tdst, tsw, bktb_d, cb_d, onorm, row, inorm,
                                  csr, NB, N);

    // ---- 3 GraphConv layers ----
    const int ab = (N + 3) / 4;
    const int gb = (N + 127) / 128;

    k_agg128<<<ab, 256, 0, stream>>>(feat, row, csr, inorm, Y, N);
    k_gemm<128, 8, true, true><<<gb, 256, 0, stream>>>(Y, W0, b0, X, N);
    k_agg128<<<ab, 256, 0, stream>>>(X, row, csr, inorm, Y, N);
    k_gemm<128, 8, true, true><<<gb, 256, 0, stream>>>(Y, W1, b1, X, N);
    k_gemm<64, 4, false, false><<<gb, 256, 0, stream>>>(X, W2, nullptr, Y, N);
    k_agg64<<<ab, 256, 0, stream>>>(Y, row, csr, inorm, b2, out, N);
}

// Round 5
// 435.369 us; speedup vs baseline: 2.0083x; 1.1791x over previous
//
#include <hip/hip_runtime.h>
#include <cstddef>
#include <cstdint>

typedef float f4 __attribute__((ext_vector_type(4)));
typedef unsigned long long u64;
typedef unsigned short u16;
typedef unsigned short u16x8 __attribute__((ext_vector_type(8)));

__device__ __forceinline__ u64 ldnt8(const void* p) {
    return __builtin_nontemporal_load((const u64*)(p));
}
// bf16 round-to-nearest-even
__device__ __forceinline__ u16 bfrn(float f) {
    unsigned u = __float_as_uint(f);
    return (u16)((u + 0x7FFFu + ((u >> 16) & 1u)) >> 16);
}
__device__ __forceinline__ float bl(unsigned w) { return __uint_as_float(w << 16); }
__device__ __forceinline__ float bh(unsigned w) { return __uint_as_float(w & 0xFFFF0000u); }

// ---------------------------------------------------------------------------
// GraphConv x3 (DGL norm='both', per-edge weight)
//   coef[e] = ew[e] * out_norm[src[e]]  (fused into CSR)
// CSR build: two-level counting sort (LDS atomics only).
// Gathered operands stored bf16; accumulation/GEMM math in fp32.
// ---------------------------------------------------------------------------

#define EPB 4096

__global__ void __launch_bounds__(256)
k_p1(const int* __restrict__ src, const int* __restrict__ dst,
     u16* __restrict__ lrank_s, u16* __restrict__ lrank_d,
     int* __restrict__ bh_s, int* __restrict__ bh_d, int NB, int E) {
    __shared__ int hs[512], hd[512];
    const int t = threadIdx.x, b = blockIdx.x;
    for (int i = t; i < NB; i += 256) { hs[i] = 0; hd[i] = 0; }
    __syncthreads();
    const int e0 = b * EPB;
    #pragma unroll
    for (int j = 0; j < 4; ++j) {
        const int e = e0 + j * 1024 + t * 4;
        if (e + 4 <= E) {
            const int4 d = *(const int4*)&dst[e];
            const int4 s = *(const int4*)&src[e];
            unsigned rd0 = atomicAdd(&hd[d.x >> 8], 1);
            unsigned rd1 = atomicAdd(&hd[d.y >> 8], 1);
            unsigned rd2 = atomicAdd(&hd[d.z >> 8], 1);
            unsigned rd3 = atomicAdd(&hd[d.w >> 8], 1);
            unsigned rs0 = atomicAdd(&hs[s.x >> 8], 1);
            unsigned rs1 = atomicAdd(&hs[s.y >> 8], 1);
            unsigned rs2 = atomicAdd(&hs[s.z >> 8], 1);
            unsigned rs3 = atomicAdd(&hs[s.w >> 8], 1);
            *(uint2*)&lrank_d[e] = make_uint2(rd0 | (rd1 << 16), rd2 | (rd3 << 16));
            *(uint2*)&lrank_s[e] = make_uint2(rs0 | (rs1 << 16), rs2 | (rs3 << 16));
        } else {
            for (int k = e; k < E && k < e + 4; ++k) {
                lrank_d[k] = (u16)atomicAdd(&hd[dst[k] >> 8], 1);
                lrank_s[k] = (u16)atomicAdd(&hs[src[k] >> 8], 1);
            }
        }
    }
    __syncthreads();
    for (int i = t; i < NB; i += 256) {
        bh_d[b * NB + i] = hd[i];
        bh_s[b * NB + i] = hs[i];
    }
}

__global__ void __launch_bounds__(512)
k_p2(int* __restrict__ bh_d, int* __restrict__ bh_s,
     int* __restrict__ cb_d, int* __restrict__ cb_s, int NB, int B1) {
    __shared__ int s[512];
    const int B = blockIdx.x, i = threadIdx.x;
    int* bh = blockIdx.y ? bh_s : bh_d;
    int* cb = blockIdx.y ? cb_s : cb_d;
    const int v = (i < B1) ? bh[i * NB + B] : 0;
    s[i] = v;
    __syncthreads();
    for (int off = 1; off < 512; off <<= 1) {
        const int x = (i >= off) ? s[i - off] : 0;
        __syncthreads();
        s[i] += x;
        __syncthreads();
    }
    if (i < B1) bh[i * NB + B] = s[i] - v;
    if (i == 511) cb[B] = s[511];
}

__global__ void __launch_bounds__(512)
k_p2b(const int* __restrict__ cb_d, const int* __restrict__ cb_s,
      int* __restrict__ bktb_d, int* __restrict__ bktb_s,
      int* __restrict__ row, int NB, int N, int E) {
    __shared__ int s[512];
    const int t = threadIdx.x;
    int v = (t < NB) ? cb_d[t] : 0;
    s[t] = v;
    __syncthreads();
    for (int off = 1; off < 512; off <<= 1) {
        const int x = (t >= off) ? s[t - off] : 0;
        __syncthreads();
        s[t] += x;
        __syncthreads();
    }
    if (t < NB) bktb_d[t] = s[t] - v;
    __syncthreads();
    v = (t < NB) ? cb_s[t] : 0;
    s[t] = v;
    __syncthreads();
    for (int off = 1; off < 512; off <<= 1) {
        const int x = (t >= off) ? s[t - off] : 0;
        __syncthreads();
        s[t] += x;
        __syncthreads();
    }
    if (t < NB) bktb_s[t] = s[t] - v;
    if (t == 0) row[N] = E;
}

__global__ void __launch_bounds__(256)
k_p3(const int* __restrict__ src, const int* __restrict__ dst,
     const float* __restrict__ ew,
     const u16* __restrict__ lrank_s, const u16* __restrict__ lrank_d,
     const int* __restrict__ bh_s, const int* __restrict__ bh_d,
     const int* __restrict__ bktb_s, const int* __restrict__ bktb_d,
     int* __restrict__ tdst, int2* __restrict__ tsw, int* __restrict__ tsrc,
     int NB, int E) {
    const int t = threadIdx.x, b = blockIdx.x;
    const int e0 = b * EPB;
    #pragma unroll
    for (int j = 0; j < 4; ++j) {
        const int e = e0 + j * 1024 + t * 4;
        if (e + 4 <= E) {
            const int4 d = *(const int4*)&dst[e];
            const int4 s = *(const int4*)&src[e];
            const f4   w = *(const f4*)&ew[e];
            const uint2 rd = *(const uint2*)&lrank_d[e];
            const uint2 rs = *(const uint2*)&lrank_s[e];
            const int dd[4] = {d.x, d.y, d.z, d.w};
            const int ss[4] = {s.x, s.y, s.z, s.w};
            const float ww[4] = {w.x, w.y, w.z, w.w};
            const int rrd[4] = {(int)(rd.x & 0xFFFF), (int)(rd.x >> 16),
                                (int)(rd.y & 0xFFFF), (int)(rd.y >> 16)};
            const int rrs[4] = {(int)(rs.x & 0xFFFF), (int)(rs.x >> 16),
                                (int)(rs.y & 0xFFFF), (int)(rs.y >> 16)};
            #pragma unroll
            for (int k = 0; k < 4; ++k) {
                const int Bd = dd[k] >> 8;
                const int posd = bktb_d[Bd] + bh_d[b * NB + Bd] + rrd[k];
                tdst[posd] = dd[k];
                tsw[posd] = make_int2(ss[k], __float_as_int(ww[k]));
                const int Bs = ss[k] >> 8;
                const int poss = bktb_s[Bs] + bh_s[b * NB + Bs] + rrs[k];
                tsrc[poss] = ss[k];
            }
        } else {
            for (int k = e; k < E && k < e + 4; ++k) {
                const int dv = dst[k], sv = src[k];
                const int Bd = dv >> 8;
                const int posd = bktb_d[Bd] + bh_d[b * NB + Bd] + (int)lrank_d[k];
                tdst[posd] = dv;
                tsw[posd] = make_int2(sv, __float_as_int(ew[k]));
                const int Bs = sv >> 8;
                const int poss = bktb_s[Bs] + bh_s[b * NB + Bs] + (int)lrank_s[k];
                tsrc[poss] = sv;
            }
        }
    }
}

__global__ void __launch_bounds__(256)
k_p4s(const int* __restrict__ tsrc, const int* __restrict__ bktb_s,
      const int* __restrict__ cb_s, float* __restrict__ onorm, int NB, int N) {
    __shared__ int cnt[256];
    const int B = blockIdx.x, t = threadIdx.x;
    cnt[t] = 0;
    __syncthreads();
    const int base = bktb_s[B], cb = cb_s[B];
    for (int i = t; i < cb; i += 256) atomicAdd(&cnt[tsrc[base + i] & 255], 1);
    __syncthreads();
    const int n = (B << 8) + t;
    if (n < N) {
        const int c = cnt[t];
        onorm[n] = rsqrtf((float)(c < 1 ? 1 : c));
    }
}

__global__ void __launch_bounds__(256)
k_p4d(const int* __restrict__ tdst, const int2* __restrict__ tsw,
      const int* __restrict__ bktb_d, const int* __restrict__ cb_d,
      const float* __restrict__ onorm, int* __restrict__ row,
      float* __restrict__ inorm, int2* __restrict__ csr, int NB, int N) {
    __shared__ int cnt[256], cnt2[256], lrow[256], sc[256];
    const int B = blockIdx.x, t = threadIdx.x;
    cnt[t] = 0; cnt2[t] = 0;
    __syncthreads();
    const int base = bktb_d[B], cb = cb_d[B];
    for (int i = t; i < cb; i += 256) atomicAdd(&cnt[tdst[base + i] & 255], 1);
    __syncthreads();
    const int v = cnt[t];
    sc[t] = v;
    __syncthreads();
    for (int off = 1; off < 256; off <<= 1) {
        const int x = (t >= off) ? sc[t - off] : 0;
        __syncthreads();
        sc[t] += x;
        __syncthreads();
    }
    const int excl = sc[t] - v;
    lrow[t] = excl;
    const int n = (B << 8) + t;
    if (n < N) {
        row[n] = base + excl;
        inorm[n] = rsqrtf((float)(v < 1 ? 1 : v));
    }
    __syncthreads();
    for (int i = t; i < cb; i += 256) {
        const int d = tdst[base + i] & 255;
        const int2 sw = tsw[base + i];
        const int r = atomicAdd(&cnt2[d], 1);
        const float coef = __int_as_float(sw.y) * onorm[sw.x];
        csr[base + lrow[d] + r] = make_int2(sw.x, __float_as_int(coef));
    }
}

// fp32 -> bf16 conversion, 8 elems/thread
__global__ void __launch_bounds__(256)
k_cvt(const float* __restrict__ in, u16* __restrict__ out, int n8) {
    const int i = blockIdx.x * blockDim.x + threadIdx.x;
    if (i < n8) {
        const f4 v0 = *(const f4*)(in + (size_t)i * 8);
        const f4 v1 = *(const f4*)(in + (size_t)i * 8 + 4);
        u16x8 r = {bfrn(v0.x), bfrn(v0.y), bfrn(v0.z), bfrn(v0.w),
                   bfrn(v1.x), bfrn(v1.y), bfrn(v1.z), bfrn(v1.w)};
        *(u16x8*)(out + (size_t)i * 8) = r;
    }
}

// one wave per node, width 128 bf16: quarter-wave per edge, 8 edges/iter
__global__ void __launch_bounds__(256)
k_agg128b(const u16* __restrict__ h, const int* __restrict__ row,
          const int2* __restrict__ csr, const float* __restrict__ inorm,
          float* __restrict__ out, int N) {
    const int node = (int)((blockIdx.x * blockDim.x + threadIdx.x) >> 6);
    if (node >= N) return;
    const int lane = threadIdx.x & 63;
    const int q = lane >> 4;
    const int col = (lane & 15) * 8;
    int p = row[node];
    const int e = row[node + 1];
    float a0 = 0, a1 = 0, a2 = 0, a3 = 0, a4 = 0, a5 = 0, a6 = 0, a7 = 0;
    for (; p + 8 <= e; p += 8) {
        const u64 c0 = ldnt8(&csr[p + q]);
        const u64 c1 = ldnt8(&csr[p + 4 + q]);
        const uint4 w0 = *(const uint4*)(h + (size_t)(int)c0 * 128 + col);
        const uint4 w1 = *(const uint4*)(h + (size_t)(int)c1 * 128 + col);
        const float f0 = __int_as_float((int)(c0 >> 32));
        const float f1 = __int_as_float((int)(c1 >> 32));
        a0 = fmaf(f0, bl(w0.x), a0); a1 = fmaf(f0, bh(w0.x), a1);
        a2 = fmaf(f0, bl(w0.y), a2); a3 = fmaf(f0, bh(w0.y), a3);
        a4 = fmaf(f0, bl(w0.z), a4); a5 = fmaf(f0, bh(w0.z), a5);
        a6 = fmaf(f0, bl(w0.w), a6); a7 = fmaf(f0, bh(w0.w), a7);
        a0 = fmaf(f1, bl(w1.x), a0); a1 = fmaf(f1, bh(w1.x), a1);
        a2 = fmaf(f1, bl(w1.y), a2); a3 = fmaf(f1, bh(w1.y), a3);
        a4 = fmaf(f1, bl(w1.z), a4); a5 = fmaf(f1, bh(w1.z), a5);
        a6 = fmaf(f1, bl(w1.w), a6); a7 = fmaf(f1, bh(w1.w), a7);
    }
    {
        const int i0 = p + q, i1 = p + 4 + q;
        if (i0 < e) {
            const u64 c = ldnt8(&csr[i0]);
            const uint4 w = *(const uint4*)(h + (size_t)(int)c * 128 + col);
            const float f = __int_as_float((int)(c >> 32));
            a0 = fmaf(f, bl(w.x), a0); a1 = fmaf(f, bh(w.x), a1);
            a2 = fmaf(f, bl(w.y), a2); a3 = fmaf(f, bh(w.y), a3);
            a4 = fmaf(f, bl(w.z), a4); a5 = fmaf(f, bh(w.z), a5);
            a6 = fmaf(f, bl(w.w), a6); a7 = fmaf(f, bh(w.w), a7);
        }
        if (i1 < e) {
            const u64 c = ldnt8(&csr[i1]);
            const uint4 w = *(const uint4*)(h + (size_t)(int)c * 128 + col);
            const float f = __int_as_float((int)(c >> 32));
            a0 = fmaf(f, bl(w.x), a0); a1 = fmaf(f, bh(w.x), a1);
            a2 = fmaf(f, bl(w.y), a2); a3 = fmaf(f, bh(w.y), a3);
            a4 = fmaf(f, bl(w.z), a4); a5 = fmaf(f, bh(w.z), a5);
            a6 = fmaf(f, bl(w.w), a6); a7 = fmaf(f, bh(w.w), a7);
        }
    }
    a0 += __shfl_xor(a0, 16); a1 += __shfl_xor(a1, 16);
    a2 += __shfl_xor(a2, 16); a3 += __shfl_xor(a3, 16);
    a4 += __shfl_xor(a4, 16); a5 += __shfl_xor(a5, 16);
    a6 += __shfl_xor(a6, 16); a7 += __shfl_xor(a7, 16);
    a0 += __shfl_xor(a0, 32); a1 += __shfl_xor(a1, 32);
    a2 += __shfl_xor(a2, 32); a3 += __shfl_xor(a3, 32);
    a4 += __shfl_xor(a4, 32); a5 += __shfl_xor(a5, 32);
    a6 += __shfl_xor(a6, 32); a7 += __shfl_xor(a7, 32);
    if (lane < 16) {
        const float nn = inorm[node];
        f4 r0 = {a0 * nn, a1 * nn, a2 * nn, a3 * nn};
        f4 r1 = {a4 * nn, a5 * nn, a6 * nn, a7 * nn};
        *(f4*)(out + (size_t)node * 128 + col) = r0;
        *(f4*)(out + (size_t)node * 128 + col + 4) = r1;
    }
}

// one wave per node, width 64 bf16: eighth-wave per edge; fused bias
__global__ void __launch_bounds__(256)
k_agg64b(const u16* __restrict__ h, const int* __restrict__ row,
         const int2* __restrict__ csr, const float* __restrict__ inorm,
         const float* __restrict__ bias, float* __restrict__ out, int N) {
    const int node = (int)((blockIdx.x * blockDim.x + threadIdx.x) >> 6);
    if (node >= N) return;
    const int lane = threadIdx.x & 63;
    const int oc = lane >> 3;
    const int col = (lane & 7) * 8;
    int p = row[node];
    const int e = row[node + 1];
    float a0 = 0, a1 = 0, a2 = 0, a3 = 0, a4 = 0, a5 = 0, a6 = 0, a7 = 0;
    for (; p + 16 <= e; p += 16) {
        const u64 c0 = ldnt8(&csr[p + oc]);
        const u64 c1 = ldnt8(&csr[p + 8 + oc]);
        const uint4 w0 = *(const uint4*)(h + (size_t)(int)c0 * 64 + col);
        const uint4 w1 = *(const uint4*)(h + (size_t)(int)c1 * 64 + col);
        const float f0 = __int_as_float((int)(c0 >> 32));
        const float f1 = __int_as_float((int)(c1 >> 32));
        a0 = fmaf(f0, bl(w0.x), a0); a1 = fmaf(f0, bh(w0.x), a1);
        a2 = fmaf(f0, bl(w0.y), a2); a3 = fmaf(f0, bh(w0.y), a3);
        a4 = fmaf(f0, bl(w0.z), a4); a5 = fmaf(f0, bh(w0.z), a5);
        a6 = fmaf(f0, bl(w0.w), a6); a7 = fmaf(f0, bh(w0.w), a7);
        a0 = fmaf(f1, bl(w1.x), a0); a1 = fmaf(f1, bh(w1.x), a1);
        a2 = fmaf(f1, bl(w1.y), a2); a3 = fmaf(f1, bh(w1.y), a3);
        a4 = fmaf(f1, bl(w1.z), a4); a5 = fmaf(f1, bh(w1.z), a5);
        a6 = fmaf(f1, bl(w1.w), a6); a7 = fmaf(f1, bh(w1.w), a7);
    }
    {
        const int i0 = p + oc, i1 = p + 8 + oc;
        if (i0 < e) {
            const u64 c = ldnt8(&csr[i0]);
            const uint4 w = *(const uint4*)(h + (size_t)(int)c * 64 + col);
            const float f = __int_as_float((int)(c >> 32));
            a0 = fmaf(f, bl(w.x), a0); a1 = fmaf(f, bh(w.x), a1);
            a2 = fmaf(f, bl(w.y), a2); a3 = fmaf(f, bh(w.y), a3);
            a4 = fmaf(f, bl(w.z), a4); a5 = fmaf(f, bh(w.z), a5);
            a6 = fmaf(f, bl(w.w), a6); a7 = fmaf(f, bh(w.w), a7);
        }
        if (i1 < e) {
            const u64 c = ldnt8(&csr[i1]);
            const uint4 w = *(const uint4*)(h + (size_t)(int)c * 64 + col);
            const float f = __int_as_float((int)(c >> 32));
            a0 = fmaf(f, bl(w.x), a0); a1 = fmaf(f, bh(w.x), a1);
            a2 = fmaf(f, bl(w.y), a2); a3 = fmaf(f, bh(w.y), a3);
            a4 = fmaf(f, bl(w.z), a4); a5 = fmaf(f, bh(w.z), a5);
            a6 = fmaf(f, bl(w.w), a6); a7 = fmaf(f, bh(w.w), a7);
        }
    }
    a0 += __shfl_xor(a0, 8);  a1 += __shfl_xor(a1, 8);
    a2 += __shfl_xor(a2, 8);  a3 += __shfl_xor(a3, 8);
    a4 += __shfl_xor(a4, 8);  a5 += __shfl_xor(a5, 8);
    a6 += __shfl_xor(a6, 8);  a7 += __shfl_xor(a7, 8);
    a0 += __shfl_xor(a0, 16); a1 += __shfl_xor(a1, 16);
    a2 += __shfl_xor(a2, 16); a3 += __shfl_xor(a3, 16);
    a4 += __shfl_xor(a4, 16); a5 += __shfl_xor(a5, 16);
    a6 += __shfl_xor(a6, 16); a7 += __shfl_xor(a7, 16);
    a0 += __shfl_xor(a0, 32); a1 += __shfl_xor(a1, 32);
    a2 += __shfl_xor(a2, 32); a3 += __shfl_xor(a3, 32);
    a4 += __shfl_xor(a4, 32); a5 += __shfl_xor(a5, 32);
    a6 += __shfl_xor(a6, 32); a7 += __shfl_xor(a7, 32);
    if (lane < 8) {
        const float nn = inorm[node];
        const f4 b0 = *(const f4*)(bias + col);
        const f4 b1 = *(const f4*)(bias + col + 4);
        f4 r0 = {a0 * nn + b0.x, a1 * nn + b0.y, a2 * nn + b0.z, a3 * nn + b0.w};
        f4 r1 = {a4 * nn + b1.x, a5 * nn + b1.y, a6 * nn + b1.z, a7 * nn + b1.w};
        *(f4*)(out + (size_t)node * 64 + col) = r0;
        *(f4*)(out + (size_t)node * 64 + col + 4) = r1;
    }
}

// C[N x BN] = A[N x 128] @ W[128 x BN] (+bias, +relu); A fp32 or bf16; C bf16
template <int BN, int TN, bool RELU, bool BIAS, bool ABF16>
__global__ void __launch_bounds__(256)
k_gemm(const void* __restrict__ Av, const float* __restrict__ W,
       const float* __restrict__ bias, u16* __restrict__ C, int N) {
    __shared__ float As[32][132];
    __shared__ float Ws[32][BN];
    const int t   = threadIdx.x;
    const int bm0 = blockIdx.x * 128;
    const int tx  = t & 15;
    const int ty  = t >> 4;

    float acc[8][TN];
    #pragma unroll
    for (int i = 0; i < 8; ++i)
        #pragma unroll
        for (int j = 0; j < TN; ++j) acc[i][j] = 0.f;

    for (int kt = 0; kt < 4; ++kt) {
        __syncthreads();
        #pragma unroll
        for (int r = 0; r < 4; ++r) {
            const int idx = r * 256 + t;
            const int m = idx >> 3, f = idx & 7;
            const int gm = bm0 + m;
            f4 v = {0.f, 0.f, 0.f, 0.f};
            if (gm < N) {
                if (ABF16) {
                    const uint2 w = *(const uint2*)((const u16*)Av + (size_t)gm * 128 + kt * 32 + f * 4);
                    v.x = bl(w.x); v.y = bh(w.x); v.z = bl(w.y); v.w = bh(w.y);
                } else {
                    v = *(const f4*)((const float*)Av + (size_t)gm * 128 + kt * 32 + f * 4);
                }
            }
            As[f * 4 + 0][m] = v.x;
            As[f * 4 + 1][m] = v.y;
            As[f * 4 + 2][m] = v.z;
            As[f * 4 + 3][m] = v.w;
        }
        #pragma unroll
        for (int r = 0; r < (BN == 128 ? 4 : 2); ++r) {
            const int idx = r * 256 + t;
            const int kk = idx / (BN / 4), f = idx % (BN / 4);
            *(f4*)&Ws[kk][f * 4] = *(const f4*)(W + (size_t)(kt * 32 + kk) * BN + f * 4);
        }
        __syncthreads();
        #pragma unroll
        for (int k = 0; k < 32; ++k) {
            const f4 a0 = *(const f4*)&As[k][ty * 8];
            const f4 a1 = *(const f4*)&As[k][ty * 8 + 4];
            const float a[8] = {a0.x, a0.y, a0.z, a0.w, a1.x, a1.y, a1.z, a1.w};
            float b[TN];
            *(f4*)&b[0] = *(const f4*)&Ws[k][tx * TN];
            if (TN == 8) *(f4*)&b[4] = *(const f4*)&Ws[k][tx * TN + 4];
            #pragma unroll
            for (int i = 0; i < 8; ++i)
                #pragma unroll
                for (int j = 0; j < TN; ++j)
                    acc[i][j] = fmaf(a[i], b[j], acc[i][j]);
        }
    }

    float bb[TN];
    #pragma unroll
    for (int j = 0; j < TN; ++j) bb[j] = BIAS ? bias[tx * TN + j] : 0.f;

    #pragma unroll
    for (int i = 0; i < 8; ++i) {
        const int gm = bm0 + ty * 8 + i;
        if (gm < N) {
            u16 us[TN];
            #pragma unroll
            for (int j = 0; j < TN; ++j) {
                float v = acc[i][j] + bb[j];
                if (RELU) v = v > 0.f ? v : 0.f;
                us[j] = bfrn(v);
            }
            #pragma unroll
            for (int j0 = 0; j0 < TN; j0 += 4)
                *(ushort4*)(C + (size_t)gm * BN + tx * TN + j0) = *(ushort4*)&us[j0];
        }
    }
}

extern "C" void kernel_launch(void* const* d_in, const int* in_sizes, int n_in,
                              void* d_out, int out_size, void* d_ws, size_t ws_size,
                              hipStream_t stream) {
    const float* feat = (const float*)d_in[0];
    const int*   src  = (const int*)d_in[1];
    const int*   dst  = (const int*)d_in[2];
    const float* ew   = (const float*)d_in[3];
    const float* W0   = (const float*)d_in[4];
    const float* b0   = (const float*)d_in[5];
    const float* W1   = (const float*)d_in[6];
    const float* b1   = (const float*)d_in[7];
    const float* W2   = (const float*)d_in[8];
    const float* b2   = (const float*)d_in[9];
    float* out = (float*)d_out;

    const int N = in_sizes[0] / 128;
    const int E = in_sizes[1];
    const int NB = (N + 255) / 256;
    const int B1 = (E + EPB - 1) / EPB;

    uint8_t* wp = (uint8_t*)d_ws;
    auto alloc = [&](size_t bytes) {
        uint8_t* r = wp;
        wp += (bytes + 511) & ~(size_t)511;
        return r;
    };
    u16*   featb = (u16*)alloc((size_t)N * 128 * 2);
    u16*   Xb    = (u16*)alloc((size_t)N * 128 * 2);   // aliases prep tables
    float* Y     = (float*)alloc((size_t)N * 128 * 4); // aliases tdst/tsw/tsrc, Gb
    int2*  csr   = (int2*)alloc((size_t)E * 8);
    int*   row   = (int*)alloc((size_t)(N + 1) * 4);
    float* onorm = (float*)alloc((size_t)N * 4);
    float* inorm = (float*)alloc((size_t)N * 4);

    // prep-phase aliases inside Xb (dead before Xb first written by gemm0)
    uint8_t* xp = (uint8_t*)Xb;
    auto xalloc = [&](size_t bytes) {
        uint8_t* r = xp;
        xp += (bytes + 511) & ~(size_t)511;
        return r;
    };
    u16* lrank_d = (u16*)xalloc((size_t)E * 2);
    u16* lrank_s = (u16*)xalloc((size_t)E * 2);
    int* bh_d    = (int*)xalloc((size_t)B1 * NB * 4);
    int* bh_s    = (int*)xalloc((size_t)B1 * NB * 4);
    int* cb_d    = (int*)xalloc((size_t)NB * 4);
    int* cb_s    = (int*)xalloc((size_t)NB * 4);
    int* bktb_d  = (int*)xalloc((size_t)NB * 4);
    int* bktb_s  = (int*)xalloc((size_t)NB * 4);

    // prep-phase + layer-2 aliases inside Y
    uint8_t* yp = (uint8_t*)Y;
    auto yalloc = [&](size_t bytes) {
        uint8_t* r = yp;
        yp += (bytes + 511) & ~(size_t)511;
        return r;
    };
    int*  tdst = (int*)yalloc((size_t)E * 4);
    int2* tsw  = (int2*)yalloc((size_t)E * 8);
    int*  tsrc = (int*)yalloc((size_t)E * 4);
    u16*  Gb   = (u16*)Y;   // written by gemm2 after Y's last read (gemm1)

    // ---- feat conversion + CSR build (LDS atomics only) ----
    k_cvt<<<(N * 128 / 8 + 255) / 256, 256, 0, stream>>>(feat, featb, N * 128 / 8);
    k_p1<<<B1, 256, 0, stream>>>(src, dst, lrank_s, lrank_d, bh_s, bh_d, NB, E);
    k_p2<<<dim3(NB, 2), 512, 0, stream>>>(bh_d, bh_s, cb_d, cb_s, NB, B1);
    k_p2b<<<1, 512, 0, stream>>>(cb_d, cb_s, bktb_d, bktb_s, row, NB, N, E);
    k_p3<<<B1, 256, 0, stream>>>(src, dst, ew, lrank_s, lrank_d, bh_s, bh_d,
                                 bktb_s, bktb_d, tdst, tsw, tsrc, NB, E);
    k_p4s<<<NB, 256, 0, stream>>>(tsrc, bktb_s, cb_s, onorm, NB, N);
    k_p4d<<<NB, 256, 0, stream>>>(tdst, tsw, bktb_d, cb_d, onorm, row, inorm,
                                  csr, NB, N);

    // ---- 3 GraphConv layers ----
    const int ab = (N + 3) / 4;
    const int gb = (N + 127) / 128;

    k_agg128b<<<ab, 256, 0, stream>>>(featb, row, csr, inorm, Y, N);
    k_gemm<128, 8, true, true, false><<<gb, 256, 0, stream>>>(Y, W0, b0, Xb, N);
    k_agg128b<<<ab, 256, 0, stream>>>(Xb, row, csr, inorm, Y, N);
    k_gemm<128, 8, true, true, false><<<gb, 256, 0, stream>>>(Y, W1, b1, Xb, N);
    k_gemm<64, 4, false, false, true><<<gb, 256, 0, stream>>>(Xb, W2, nullptr, Gb, N);
    k_agg64b<<<ab, 256, 0, stream>>>(Gb, row, csr, inorm, b2, out, N);
}

// Round 6
// 338.706 us; speedup vs baseline: 2.5814x; 1.2854x over previous
//
#include <hip/hip_runtime.h>
#include <cstddef>
#include <cstdint>

typedef float f4 __attribute__((ext_vector_type(4)));
typedef unsigned long long u64;
typedef unsigned short u16;
typedef unsigned short u16x8 __attribute__((ext_vector_type(8)));
typedef short short8 __attribute__((ext_vector_type(8)));

__device__ __forceinline__ u64 ldnt8(const void* p) {
    return __builtin_nontemporal_load((const u64*)(p));
}
// bf16 round-to-nearest-even
__device__ __forceinline__ u16 bfrn(float f) {
    unsigned u = __float_as_uint(f);
    return (u16)((u + 0x7FFFu + ((u >> 16) & 1u)) >> 16);
}
__device__ __forceinline__ float bl(unsigned w) { return __uint_as_float(w << 16); }
__device__ __forceinline__ float bh(unsigned w) { return __uint_as_float(w & 0xFFFF0000u); }

// ---------------------------------------------------------------------------
// GraphConv x3 (DGL norm='both', per-edge weight)
//   coef[e] = ew[e] * out_norm[src[e]]  (fused into CSR)
// CSR build: two-level counting sort (LDS atomics only).
// Gathered operands + GEMM operands bf16; accumulation fp32 (MFMA).
// ---------------------------------------------------------------------------

#define EPB 4096

__global__ void __launch_bounds__(256)
k_p1(const int* __restrict__ src, const int* __restrict__ dst,
     u16* __restrict__ lrank_s, u16* __restrict__ lrank_d,
     int* __restrict__ bh_s, int* __restrict__ bh_d, int NB, int E) {
    __shared__ int hs[512], hd[512];
    const int t = threadIdx.x, b = blockIdx.x;
    for (int i = t; i < NB; i += 256) { hs[i] = 0; hd[i] = 0; }
    __syncthreads();
    const int e0 = b * EPB;
    #pragma unroll
    for (int j = 0; j < 4; ++j) {
        const int e = e0 + j * 1024 + t * 4;
        if (e + 4 <= E) {
            const int4 d = *(const int4*)&dst[e];
            const int4 s = *(const int4*)&src[e];
            unsigned rd0 = atomicAdd(&hd[d.x >> 8], 1);
            unsigned rd1 = atomicAdd(&hd[d.y >> 8], 1);
            unsigned rd2 = atomicAdd(&hd[d.z >> 8], 1);
            unsigned rd3 = atomicAdd(&hd[d.w >> 8], 1);
            unsigned rs0 = atomicAdd(&hs[s.x >> 8], 1);
            unsigned rs1 = atomicAdd(&hs[s.y >> 8], 1);
            unsigned rs2 = atomicAdd(&hs[s.z >> 8], 1);
            unsigned rs3 = atomicAdd(&hs[s.w >> 8], 1);
            *(uint2*)&lrank_d[e] = make_uint2(rd0 | (rd1 << 16), rd2 | (rd3 << 16));
            *(uint2*)&lrank_s[e] = make_uint2(rs0 | (rs1 << 16), rs2 | (rs3 << 16));
        } else {
            for (int k = e; k < E && k < e + 4; ++k) {
                lrank_d[k] = (u16)atomicAdd(&hd[dst[k] >> 8], 1);
                lrank_s[k] = (u16)atomicAdd(&hs[src[k] >> 8], 1);
            }
        }
    }
    __syncthreads();
    for (int i = t; i < NB; i += 256) {
        bh_d[b * NB + i] = hd[i];
        bh_s[b * NB + i] = hs[i];
    }
}

__global__ void __launch_bounds__(512)
k_p2(int* __restrict__ bh_d, int* __restrict__ bh_s,
     int* __restrict__ cb_d, int* __restrict__ cb_s, int NB, int B1) {
    __shared__ int s[512];
    const int B = blockIdx.x, i = threadIdx.x;
    int* bh = blockIdx.y ? bh_s : bh_d;
    int* cb = blockIdx.y ? cb_s : cb_d;
    const int v = (i < B1) ? bh[i * NB + B] : 0;
    s[i] = v;
    __syncthreads();
    for (int off = 1; off < 512; off <<= 1) {
        const int x = (i >= off) ? s[i - off] : 0;
        __syncthreads();
        s[i] += x;
        __syncthreads();
    }
    if (i < B1) bh[i * NB + B] = s[i] - v;
    if (i == 511) cb[B] = s[511];
}

__global__ void __launch_bounds__(512)
k_p2b(const int* __restrict__ cb_d, const int* __restrict__ cb_s,
      int* __restrict__ bktb_d, int* __restrict__ bktb_s,
      int* __restrict__ row, int NB, int N, int E) {
    __shared__ int s[512];
    const int t = threadIdx.x;
    int v = (t < NB) ? cb_d[t] : 0;
    s[t] = v;
    __syncthreads();
    for (int off = 1; off < 512; off <<= 1) {
        const int x = (t >= off) ? s[t - off] : 0;
        __syncthreads();
        s[t] += x;
        __syncthreads();
    }
    if (t < NB) bktb_d[t] = s[t] - v;
    __syncthreads();
    v = (t < NB) ? cb_s[t] : 0;
    s[t] = v;
    __syncthreads();
    for (int off = 1; off < 512; off <<= 1) {
        const int x = (t >= off) ? s[t - off] : 0;
        __syncthreads();
        s[t] += x;
        __syncthreads();
    }
    if (t < NB) bktb_s[t] = s[t] - v;
    if (t == 0) row[N] = E;
}

__global__ void __launch_bounds__(256)
k_p3(const int* __restrict__ src, const int* __restrict__ dst,
     const float* __restrict__ ew,
     const u16* __restrict__ lrank_s, const u16* __restrict__ lrank_d,
     const int* __restrict__ bh_s, const int* __restrict__ bh_d,
     const int* __restrict__ bktb_s, const int* __restrict__ bktb_d,
     int* __restrict__ tdst, int2* __restrict__ tsw, int* __restrict__ tsrc,
     int NB, int E) {
    const int t = threadIdx.x, b = blockIdx.x;
    const int e0 = b * EPB;
    #pragma unroll
    for (int j = 0; j < 4; ++j) {
        const int e = e0 + j * 1024 + t * 4;
        if (e + 4 <= E) {
            const int4 d = *(const int4*)&dst[e];
            const int4 s = *(const int4*)&src[e];
            const f4   w = *(const f4*)&ew[e];
            const uint2 rd = *(const uint2*)&lrank_d[e];
            const uint2 rs = *(const uint2*)&lrank_s[e];
            const int dd[4] = {d.x, d.y, d.z, d.w};
            const int ss[4] = {s.x, s.y, s.z, s.w};
            const float ww[4] = {w.x, w.y, w.z, w.w};
            const int rrd[4] = {(int)(rd.x & 0xFFFF), (int)(rd.x >> 16),
                                (int)(rd.y & 0xFFFF), (int)(rd.y >> 16)};
            const int rrs[4] = {(int)(rs.x & 0xFFFF), (int)(rs.x >> 16),
                                (int)(rs.y & 0xFFFF), (int)(rs.y >> 16)};
            #pragma unroll
            for (int k = 0; k < 4; ++k) {
                const int Bd = dd[k] >> 8;
                const int posd = bktb_d[Bd] + bh_d[b * NB + Bd] + rrd[k];
                tdst[posd] = dd[k];
                tsw[posd] = make_int2(ss[k], __float_as_int(ww[k]));
                const int Bs = ss[k] >> 8;
                const int poss = bktb_s[Bs] + bh_s[b * NB + Bs] + rrs[k];
                tsrc[poss] = ss[k];
            }
        } else {
            for (int k = e; k < E && k < e + 4; ++k) {
                const int dv = dst[k], sv = src[k];
                const int Bd = dv >> 8;
                const int posd = bktb_d[Bd] + bh_d[b * NB + Bd] + (int)lrank_d[k];
                tdst[posd] = dv;
                tsw[posd] = make_int2(sv, __float_as_int(ew[k]));
                const int Bs = sv >> 8;
                const int poss = bktb_s[Bs] + bh_s[b * NB + Bs] + (int)lrank_s[k];
                tsrc[poss] = sv;
            }
        }
    }
}

__global__ void __launch_bounds__(256)
k_p4s(const int* __restrict__ tsrc, const int* __restrict__ bktb_s,
      const int* __restrict__ cb_s, float* __restrict__ onorm, int NB, int N) {
    __shared__ int cnt[256];
    const int B = blockIdx.x, t = threadIdx.x;
    cnt[t] = 0;
    __syncthreads();
    const int base = bktb_s[B], cb = cb_s[B];
    for (int i = t; i < cb; i += 256) atomicAdd(&cnt[tsrc[base + i] & 255], 1);
    __syncthreads();
    const int n = (B << 8) + t;
    if (n < N) {
        const int c = cnt[t];
        onorm[n] = rsqrtf((float)(c < 1 ? 1 : c));
    }
}

__global__ void __launch_bounds__(256)
k_p4d(const int* __restrict__ tdst, const int2* __restrict__ tsw,
      const int* __restrict__ bktb_d, const int* __restrict__ cb_d,
      const float* __restrict__ onorm, int* __restrict__ row,
      float* __restrict__ inorm, int2* __restrict__ csr, int NB, int N) {
    __shared__ int cnt[256], cnt2[256], lrow[256], sc[256];
    const int B = blockIdx.x, t = threadIdx.x;
    cnt[t] = 0; cnt2[t] = 0;
    __syncthreads();
    const int base = bktb_d[B], cb = cb_d[B];
    for (int i = t; i < cb; i += 256) atomicAdd(&cnt[tdst[base + i] & 255], 1);
    __syncthreads();
    const int v = cnt[t];
    sc[t] = v;
    __syncthreads();
    for (int off = 1; off < 256; off <<= 1) {
        const int x = (t >= off) ? sc[t - off] : 0;
        __syncthreads();
        sc[t] += x;
        __syncthreads();
    }
    const int excl = sc[t] - v;
    lrow[t] = excl;
    const int n = (B << 8) + t;
    if (n < N) {
        row[n] = base + excl;
        inorm[n] = rsqrtf((float)(v < 1 ? 1 : v));
    }
    __syncthreads();
    for (int i = t; i < cb; i += 256) {
        const int d = tdst[base + i] & 255;
        const int2 sw = tsw[base + i];
        const int r = atomicAdd(&cnt2[d], 1);
        const float coef = __int_as_float(sw.y) * onorm[sw.x];
        csr[base + lrow[d] + r] = make_int2(sw.x, __float_as_int(coef));
    }
}

// fp32 -> bf16 conversion, 8 elems/thread
__global__ void __launch_bounds__(256)
k_cvt(const float* __restrict__ in, u16* __restrict__ out, int n8) {
    const int i = blockIdx.x * blockDim.x + threadIdx.x;
    if (i < n8) {
        const f4 v0 = *(const f4*)(in + (size_t)i * 8);
        const f4 v1 = *(const f4*)(in + (size_t)i * 8 + 4);
        u16x8 r = {bfrn(v0.x), bfrn(v0.y), bfrn(v0.z), bfrn(v0.w),
                   bfrn(v1.x), bfrn(v1.y), bfrn(v1.z), bfrn(v1.w)};
        *(u16x8*)(out + (size_t)i * 8) = r;
    }
}

// W [K x COLS] fp32 -> Wt [COLS x K] bf16 (transposed, fragment-friendly)
template <int LOGC>
__global__ void __launch_bounds__(256)
k_wcvt(const float* __restrict__ W, u16* __restrict__ Wt, int K) {
    const int idx = blockIdx.x * 256 + threadIdx.x;
    if (idx < (K << LOGC)) {
        const int k = idx >> LOGC;
        const int c = idx & ((1 << LOGC) - 1);
        Wt[(size_t)c * K + k] = bfrn(W[idx]);
    }
}

// one wave per node, width 128 bf16: quarter-wave per edge, 16 edges/iter
__global__ void __launch_bounds__(256)
k_agg128b(const u16* __restrict__ h, const int* __restrict__ row,
          const int2* __restrict__ csr, const float* __restrict__ inorm,
          u16* __restrict__ out, int N) {
    const int node = (int)((blockIdx.x * blockDim.x + threadIdx.x) >> 6);
    if (node >= N) return;
    const int lane = threadIdx.x & 63;
    const int q = lane >> 4;
    const int col = (lane & 15) * 8;
    int p = row[node];
    const int e = row[node + 1];
    float a0 = 0, a1 = 0, a2 = 0, a3 = 0, a4 = 0, a5 = 0, a6 = 0, a7 = 0;
    for (; p + 16 <= e; p += 16) {
        const u64 c0 = ldnt8(&csr[p + q]);
        const u64 c1 = ldnt8(&csr[p + 4 + q]);
        const u64 c2 = ldnt8(&csr[p + 8 + q]);
        const u64 c3 = ldnt8(&csr[p + 12 + q]);
        const uint4 w0 = *(const uint4*)(h + (size_t)(int)c0 * 128 + col);
        const uint4 w1 = *(const uint4*)(h + (size_t)(int)c1 * 128 + col);
        const uint4 w2 = *(const uint4*)(h + (size_t)(int)c2 * 128 + col);
        const uint4 w3 = *(const uint4*)(h + (size_t)(int)c3 * 128 + col);
        const float f0 = __int_as_float((int)(c0 >> 32));
        const float f1 = __int_as_float((int)(c1 >> 32));
        const float f2 = __int_as_float((int)(c2 >> 32));
        const float f3 = __int_as_float((int)(c3 >> 32));
        a0 = fmaf(f0, bl(w0.x), a0); a1 = fmaf(f0, bh(w0.x), a1);
        a2 = fmaf(f0, bl(w0.y), a2); a3 = fmaf(f0, bh(w0.y), a3);
        a4 = fmaf(f0, bl(w0.z), a4); a5 = fmaf(f0, bh(w0.z), a5);
        a6 = fmaf(f0, bl(w0.w), a6); a7 = fmaf(f0, bh(w0.w), a7);
        a0 = fmaf(f1, bl(w1.x), a0); a1 = fmaf(f1, bh(w1.x), a1);
        a2 = fmaf(f1, bl(w1.y), a2); a3 = fmaf(f1, bh(w1.y), a3);
        a4 = fmaf(f1, bl(w1.z), a4); a5 = fmaf(f1, bh(w1.z), a5);
        a6 = fmaf(f1, bl(w1.w), a6); a7 = fmaf(f1, bh(w1.w), a7);
        a0 = fmaf(f2, bl(w2.x), a0); a1 = fmaf(f2, bh(w2.x), a1);
        a2 = fmaf(f2, bl(w2.y), a2); a3 = fmaf(f2, bh(w2.y), a3);
        a4 = fmaf(f2, bl(w2.z), a4); a5 = fmaf(f2, bh(w2.z), a5);
        a6 = fmaf(f2, bl(w2.w), a6); a7 = fmaf(f2, bh(w2.w), a7);
        a0 = fmaf(f3, bl(w3.x), a0); a1 = fmaf(f3, bh(w3.x), a1);
        a2 = fmaf(f3, bl(w3.y), a2); a3 = fmaf(f3, bh(w3.y), a3);
        a4 = fmaf(f3, bl(w3.z), a4); a5 = fmaf(f3, bh(w3.z), a5);
        a6 = fmaf(f3, bl(w3.w), a6); a7 = fmaf(f3, bh(w3.w), a7);
    }
    for (; p + 8 <= e; p += 8) {
        const u64 c0 = ldnt8(&csr[p + q]);
        const u64 c1 = ldnt8(&csr[p + 4 + q]);
        const uint4 w0 = *(const uint4*)(h + (size_t)(int)c0 * 128 + col);
        const uint4 w1 = *(const uint4*)(h + (size_t)(int)c1 * 128 + col);
        const float f0 = __int_as_float((int)(c0 >> 32));
        const float f1 = __int_as_float((int)(c1 >> 32));
        a0 = fmaf(f0, bl(w0.x), a0); a1 = fmaf(f0, bh(w0.x), a1);
        a2 = fmaf(f0, bl(w0.y), a2); a3 = fmaf(f0, bh(w0.y), a3);
        a4 = fmaf(f0, bl(w0.z), a4); a5 = fmaf(f0, bh(w0.z), a5);
        a6 = fmaf(f0, bl(w0.w), a6); a7 = fmaf(f0, bh(w0.w), a7);
        a0 = fmaf(f1, bl(w1.x), a0); a1 = fmaf(f1, bh(w1.x), a1);
        a2 = fmaf(f1, bl(w1.y), a2); a3 = fmaf(f1, bh(w1.y), a3);
        a4 = fmaf(f1, bl(w1.z), a4); a5 = fmaf(f1, bh(w1.z), a5);
        a6 = fmaf(f1, bl(w1.w), a6); a7 = fmaf(f1, bh(w1.w), a7);
    }
    {
        const int i0 = p + q, i1 = p + 4 + q;
        if (i0 < e) {
            const u64 c = ldnt8(&csr[i0]);
            const uint4 w = *(const uint4*)(h + (size_t)(int)c * 128 + col);
            const float f = __int_as_float((int)(c >> 32));
            a0 = fmaf(f, bl(w.x), a0); a1 = fmaf(f, bh(w.x), a1);
            a2 = fmaf(f, bl(w.y), a2); a3 = fmaf(f, bh(w.y), a3);
            a4 = fmaf(f, bl(w.z), a4); a5 = fmaf(f, bh(w.z), a5);
            a6 = fmaf(f, bl(w.w), a6); a7 = fmaf(f, bh(w.w), a7);
        }
        if (i1 < e) {
            const u64 c = ldnt8(&csr[i1]);
            const uint4 w = *(const uint4*)(h + (size_t)(int)c * 128 + col);
            const float f = __int_as_float((int)(c >> 32));
            a0 = fmaf(f, bl(w.x), a0); a1 = fmaf(f, bh(w.x), a1);
            a2 = fmaf(f, bl(w.y), a2); a3 = fmaf(f, bh(w.y), a3);
            a4 = fmaf(f, bl(w.z), a4); a5 = fmaf(f, bh(w.z), a5);
            a6 = fmaf(f, bl(w.w), a6); a7 = fmaf(f, bh(w.w), a7);
        }
    }
    a0 += __shfl_xor(a0, 16); a1 += __shfl_xor(a1, 16);
    a2 += __shfl_xor(a2, 16); a3 += __shfl_xor(a3, 16);
    a4 += __shfl_xor(a4, 16); a5 += __shfl_xor(a5, 16);
    a6 += __shfl_xor(a6, 16); a7 += __shfl_xor(a7, 16);
    a0 += __shfl_xor(a0, 32); a1 += __shfl_xor(a1, 32);
    a2 += __shfl_xor(a2, 32); a3 += __shfl_xor(a3, 32);
    a4 += __shfl_xor(a4, 32); a5 += __shfl_xor(a5, 32);
    a6 += __shfl_xor(a6, 32); a7 += __shfl_xor(a7, 32);
    if (lane < 16) {
        const float nn = inorm[node];
        u16x8 r = {bfrn(a0 * nn), bfrn(a1 * nn), bfrn(a2 * nn), bfrn(a3 * nn),
                   bfrn(a4 * nn), bfrn(a5 * nn), bfrn(a6 * nn), bfrn(a7 * nn)};
        *(u16x8*)(out + (size_t)node * 128 + col) = r;
    }
}

// one wave per node, width 64 bf16: eighth-wave per edge; fused bias; fp32 out
__global__ void __launch_bounds__(256)
k_agg64b(const u16* __restrict__ h, const int* __restrict__ row,
         const int2* __restrict__ csr, const float* __restrict__ inorm,
         const float* __restrict__ bias, float* __restrict__ out, int N) {
    const int node = (int)((blockIdx.x * blockDim.x + threadIdx.x) >> 6);
    if (node >= N) return;
    const int lane = threadIdx.x & 63;
    const int oc = lane >> 3;
    const int col = (lane & 7) * 8;
    int p = row[node];
    const int e = row[node + 1];
    float a0 = 0, a1 = 0, a2 = 0, a3 = 0, a4 = 0, a5 = 0, a6 = 0, a7 = 0;
    for (; p + 16 <= e; p += 16) {
        const u64 c0 = ldnt8(&csr[p + oc]);
        const u64 c1 = ldnt8(&csr[p + 8 + oc]);
        const uint4 w0 = *(const uint4*)(h + (size_t)(int)c0 * 64 + col);
        const uint4 w1 = *(const uint4*)(h + (size_t)(int)c1 * 64 + col);
        const float f0 = __int_as_float((int)(c0 >> 32));
        const float f1 = __int_as_float((int)(c1 >> 32));
        a0 = fmaf(f0, bl(w0.x), a0); a1 = fmaf(f0, bh(w0.x), a1);
        a2 = fmaf(f0, bl(w0.y), a2); a3 = fmaf(f0, bh(w0.y), a3);
        a4 = fmaf(f0, bl(w0.z), a4); a5 = fmaf(f0, bh(w0.z), a5);
        a6 = fmaf(f0, bl(w0.w), a6); a7 = fmaf(f0, bh(w0.w), a7);
        a0 = fmaf(f1, bl(w1.x), a0); a1 = fmaf(f1, bh(w1.x), a1);
        a2 = fmaf(f1, bl(w1.y), a2); a3 = fmaf(f1, bh(w1.y), a3);
        a4 = fmaf(f1, bl(w1.z), a4); a5 = fmaf(f1, bh(w1.z), a5);
        a6 = fmaf(f1, bl(w1.w), a6); a7 = fmaf(f1, bh(w1.w), a7);
    }
    {
        const int i0 = p + oc, i1 = p + 8 + oc;
        if (i0 < e) {
            const u64 c = ldnt8(&csr[i0]);
            const uint4 w = *(const uint4*)(h + (size_t)(int)c * 64 + col);
            const float f = __int_as_float((int)(c >> 32));
            a0 = fmaf(f, bl(w.x), a0); a1 = fmaf(f, bh(w.x), a1);
            a2 = fmaf(f, bl(w.y), a2); a3 = fmaf(f, bh(w.y), a3);
            a4 = fmaf(f, bl(w.z), a4); a5 = fmaf(f, bh(w.z), a5);
            a6 = fmaf(f, bl(w.w), a6); a7 = fmaf(f, bh(w.w), a7);
        }
        if (i1 < e) {
            const u64 c = ldnt8(&csr[i1]);
            const uint4 w = *(const uint4*)(h + (size_t)(int)c * 64 + col);
            const float f = __int_as_float((int)(c >> 32));
            a0 = fmaf(f, bl(w.x), a0); a1 = fmaf(f, bh(w.x), a1);
            a2 = fmaf(f, bl(w.y), a2); a3 = fmaf(f, bh(w.y), a3);
            a4 = fmaf(f, bl(w.z), a4); a5 = fmaf(f, bh(w.z), a5);
            a6 = fmaf(f, bl(w.w), a6); a7 = fmaf(f, bh(w.w), a7);
        }
    }
    a0 += __shfl_xor(a0, 8);  a1 += __shfl_xor(a1, 8);
    a2 += __shfl_xor(a2, 8);  a3 += __shfl_xor(a3, 8);
    a4 += __shfl_xor(a4, 8);  a5 += __shfl_xor(a5, 8);
    a6 += __shfl_xor(a6, 8);  a7 += __shfl_xor(a7, 8);
    a0 += __shfl_xor(a0, 16); a1 += __shfl_xor(a1, 16);
    a2 += __shfl_xor(a2, 16); a3 += __shfl_xor(a3, 16);
    a4 += __shfl_xor(a4, 16); a5 += __shfl_xor(a5, 16);
    a6 += __shfl_xor(a6, 16); a7 += __shfl_xor(a7, 16);
    a0 += __shfl_xor(a0, 32); a1 += __shfl_xor(a1, 32);
    a2 += __shfl_xor(a2, 32); a3 += __shfl_xor(a3, 32);
    a4 += __shfl_xor(a4, 32); a5 += __shfl_xor(a5, 32);
    a6 += __shfl_xor(a6, 32); a7 += __shfl_xor(a7, 32);
    if (lane < 8) {
        const float nn = inorm[node];
        const f4 b0 = *(const f4*)(bias + col);
        const f4 b1 = *(const f4*)(bias + col + 4);
        f4 r0 = {a0 * nn + b0.x, a1 * nn + b0.y, a2 * nn + b0.z, a3 * nn + b0.w};
        f4 r1 = {a4 * nn + b1.x, a5 * nn + b1.y, a6 * nn + b1.z, a7 * nn + b1.w};
        *(f4*)(out + (size_t)node * 64 + col) = r0;
        *(f4*)(out + (size_t)node * 64 + col + 4) = r1;
    }
}

// MFMA GEMM: C[N x COLS] = A[N x 128] @ W[128 x COLS] (+bias,+relu), bf16 io.
// Wt is W transposed [COLS x 128] bf16. 256 thr = 4 waves, 64 rows/block,
// 16 rows/wave via mfma_f32_16x16x32_bf16 (A: row=l&15,k=(l>>4)*8+j;
// B: col=l&15, same k; C/D: col=l&15,row=(l>>4)*4+reg — guide-verified).
template <int COLS, bool RELU, bool BIAS>
__global__ void __launch_bounds__(256)
k_mgemm(const u16* __restrict__ A, const u16* __restrict__ Wt,
        const float* __restrict__ bias, u16* __restrict__ C, int N) {
    __shared__ u16 Wl[COLS][136];    // 272B pitch: 2-way LDS conflicts only
    const int t = threadIdx.x;
    const int lane = t & 63;
    const int wave = t >> 6;
    // stage Wt (COLS*128 bf16) into LDS, coalesced 16B chunks
    #pragma unroll
    for (int i = 0; i < COLS / 16; ++i) {      // COLS*128/(256*8)
        const int elem = (i * 256 + t) * 8;
        const int r = elem >> 7, c0 = elem & 127;
        *(short8*)&Wl[r][c0] = *(const short8*)(Wt + elem);
    }
    const int row0 = blockIdx.x * 64 + wave * 16;
    const int arow = min(row0 + (lane & 15), N - 1);
    const int koff = (lane >> 4) * 8;
    short8 a[4];
    #pragma unroll
    for (int kk = 0; kk < 4; ++kk)
        a[kk] = *(const short8*)(A + (size_t)arow * 128 + kk * 32 + koff);
    __syncthreads();

    f4 acc[COLS / 16];
    #pragma unroll
    for (int ct = 0; ct < COLS / 16; ++ct) acc[ct] = (f4){0.f, 0.f, 0.f, 0.f};

    #pragma unroll
    for (int ct = 0; ct < COLS / 16; ++ct) {
        #pragma unroll
        for (int kk = 0; kk < 4; ++kk) {
            const short8 b = *(const short8*)&Wl[ct * 16 + (lane & 15)][kk * 32 + koff];
            acc[ct] = __builtin_amdgcn_mfma_f32_16x16x32_bf16(a[kk], b, acc[ct], 0, 0, 0);
        }
    }

    #pragma unroll
    for (int ct = 0; ct < COLS / 16; ++ct) {
        const int c = ct * 16 + (lane & 15);
        const float bb = BIAS ? bias[c] : 0.f;
        #pragma unroll
        for (int r = 0; r < 4; ++r) {
            const int gr = row0 + (lane >> 4) * 4 + r;
            if (gr < N) {
                float v = acc[ct][r] + bb;
                if (RELU) v = v > 0.f ? v : 0.f;
                C[(size_t)gr * COLS + c] = bfrn(v);
            }
        }
    }
}

extern "C" void kernel_launch(void* const* d_in, const int* in_sizes, int n_in,
                              void* d_out, int out_size, void* d_ws, size_t ws_size,
                              hipStream_t stream) {
    const float* feat = (const float*)d_in[0];
    const int*   src  = (const int*)d_in[1];
    const int*   dst  = (const int*)d_in[2];
    const float* ew   = (const float*)d_in[3];
    const float* W0   = (const float*)d_in[4];
    const float* b0   = (const float*)d_in[5];
    const float* W1   = (const float*)d_in[6];
    const float* b1   = (const float*)d_in[7];
    const float* W2   = (const float*)d_in[8];
    const float* b2   = (const float*)d_in[9];
    float* out = (float*)d_out;

    const int N = in_sizes[0] / 128;
    const int E = in_sizes[1];
    const int NB = (N + 255) / 256;
    const int B1 = (E + EPB - 1) / EPB;

    uint8_t* wp = (uint8_t*)d_ws;
    auto alloc = [&](size_t bytes) {
        uint8_t* r = wp;
        wp += (bytes + 511) & ~(size_t)511;
        return r;
    };
    u16*   featb = (u16*)alloc((size_t)N * 128 * 2);
    u16*   Xb    = (u16*)alloc((size_t)N * 128 * 2);        // aliases prep tables
    u16*   Yb    = (u16*)alloc((size_t)N * 128 * 2 + 65536); // aliases tdst/tsw/tsrc, Gb
    int2*  csr   = (int2*)alloc((size_t)E * 8);
    int*   row   = (int*)alloc((size_t)(N + 1) * 4);
    float* onorm = (float*)alloc((size_t)N * 4);
    float* inorm = (float*)alloc((size_t)N * 4);
    u16*   Wt0   = (u16*)alloc(128 * 128 * 2);
    u16*   Wt1   = (u16*)alloc(128 * 128 * 2);
    u16*   Wt2   = (u16*)alloc(128 * 64 * 2);

    // prep-phase aliases inside Xb (dead before Xb first written by gemm0)
    uint8_t* xp = (uint8_t*)Xb;
    auto xalloc = [&](size_t bytes) {
        uint8_t* r = xp;
        xp += (bytes + 511) & ~(size_t)511;
        return r;
    };
    u16* lrank_d = (u16*)xalloc((size_t)E * 2);
    u16* lrank_s = (u16*)xalloc((size_t)E * 2);
    int* bh_d    = (int*)xalloc((size_t)B1 * NB * 4);
    int* bh_s    = (int*)xalloc((size_t)B1 * NB * 4);
    int* cb_d    = (int*)xalloc((size_t)NB * 4);
    int* cb_s    = (int*)xalloc((size_t)NB * 4);
    int* bktb_d  = (int*)xalloc((size_t)NB * 4);
    int* bktb_s  = (int*)xalloc((size_t)NB * 4);

    // prep-phase + layer-2 aliases inside Yb
    uint8_t* yp = (uint8_t*)Yb;
    auto yalloc = [&](size_t bytes) {
        uint8_t* r = yp;
        yp += (bytes + 511) & ~(size_t)511;
        return r;
    };
    int*  tdst = (int*)yalloc((size_t)E * 4);
    int2* tsw  = (int2*)yalloc((size_t)E * 8);
    int*  tsrc = (int*)yalloc((size_t)E * 4);
    u16*  Gb   = (u16*)Yb;   // written by gemm2 after Yb's last read (gemm1)

    // ---- conversions + CSR build (LDS atomics only) ----
    k_cvt<<<(N * 128 / 8 + 255) / 256, 256, 0, stream>>>(feat, featb, N * 128 / 8);
    k_wcvt<7><<<64, 256, 0, stream>>>(W0, Wt0, 128);
    k_wcvt<7><<<64, 256, 0, stream>>>(W1, Wt1, 128);
    k_wcvt<6><<<32, 256, 0, stream>>>(W2, Wt2, 128);
    k_p1<<<B1, 256, 0, stream>>>(src, dst, lrank_s, lrank_d, bh_s, bh_d, NB, E);
    k_p2<<<dim3(NB, 2), 512, 0, stream>>>(bh_d, bh_s, cb_d, cb_s, NB, B1);
    k_p2b<<<1, 512, 0, stream>>>(cb_d, cb_s, bktb_d, bktb_s, row, NB, N, E);
    k_p3<<<B1, 256, 0, stream>>>(src, dst, ew, lrank_s, lrank_d, bh_s, bh_d,
                                 bktb_s, bktb_d, tdst, tsw, tsrc, NB, E);
    k_p4s<<<NB, 256, 0, stream>>>(tsrc, bktb_s, cb_s, onorm, NB, N);
    k_p4d<<<NB, 256, 0, stream>>>(tdst, tsw, bktb_d, cb_d, onorm, row, inorm,
                                  csr, NB, N);

    // ---- 3 GraphConv layers ----
    const int ab = (N + 3) / 4;
    const int gb = (N + 63) / 64;

    k_agg128b<<<ab, 256, 0, stream>>>(featb, row, csr, inorm, Yb, N);
    k_mgemm<128, true, true><<<gb, 256, 0, stream>>>(Yb, Wt0, b0, Xb, N);
    k_agg128b<<<ab, 256, 0, stream>>>(Xb, row, csr, inorm, Yb, N);
    k_mgemm<128, true, true><<<gb, 256, 0, stream>>>(Yb, Wt1, b1, Xb, N);
    k_mgemm<64, false, false><<<gb, 256, 0, stream>>>(Xb, Wt2, nullptr, Gb, N);
    k_agg64b<<<ab, 256, 0, stream>>>(Gb, row, csr, inorm, b2, out, N);
}